// Round 8
// baseline (279.046 us; speedup 1.0000x reference)
//
#include <hip/hip_runtime.h>

typedef unsigned short u16;
typedef __attribute__((ext_vector_type(4))) unsigned short u16x4;
typedef __attribute__((ext_vector_type(8))) unsigned short u16x8;
typedef __attribute__((ext_vector_type(4))) short s16x4;
typedef __attribute__((ext_vector_type(8))) short s16x8;
typedef __attribute__((ext_vector_type(4))) float f32x4;

__device__ __forceinline__ u16 f2bf(float f) {
  unsigned int u = __float_as_uint(f);
  u += 0x7FFFu + ((u >> 16) & 1u);   // RNE
  return (u16)(u >> 16);
}
__device__ __forceinline__ float bf2f(u16 h) {
  return __uint_as_float(((unsigned int)h) << 16);
}

// async global->LDS, 16B per lane; base = lane0's lds ptr, lane i writes base+i*16B.
__device__ __forceinline__ void gload_lds16(const u16* g, u16* l) {
  __builtin_amdgcn_global_load_lds(
      (const __attribute__((address_space(1))) unsigned int*)(g),
      (__attribute__((address_space(3))) unsigned int*)(l), 16, 0, 0);
}

// ---------------- fused fp32 -> bf16 convert: x + all four weights ----------------
__global__ __launch_bounds__(256) void cvt_all(const float* __restrict__ x,
                                               const float* __restrict__ Wq,
                                               const float* __restrict__ Wk,
                                               const float* __restrict__ Wv,
                                               const float* __restrict__ Wo,
                                               u16* __restrict__ xbf,
                                               u16* __restrict__ wbf,
                                               u16* __restrict__ wobf) {
  int blk = blockIdx.x;                // 0..8191
  const float* src;
  u16* dst;
  int i;
  if (blk < 4096) {
    src = x; dst = xbf; i = blk * 256 + threadIdx.x;
  } else {
    int wb = blk - 4096;               // 0..4095
    int sel = wb >> 10;
    src = (sel == 0) ? Wq : (sel == 1) ? Wk : (sel == 2) ? Wv : Wo;
    dst = (sel < 3) ? (wbf + (size_t)sel * 1048576) : wobf;
    i = (wb & 1023) * 256 + threadIdx.x;
  }
  float4 v = reinterpret_cast<const float4*>(src)[i];
  u16x4 o;
  o.x = f2bf(v.x); o.y = f2bf(v.y); o.z = f2bf(v.z); o.w = f2bf(v.w);
  reinterpret_cast<u16x4*>(dst)[i] = o;
}

// ---------------- templated GEMM, BK=32, double-buffered, XCD-chunked swizzle ----------------
__device__ __forceinline__ void store_out(float* p, float v) { *p = v; }
__device__ __forceinline__ void store_out(u16* p, float v) { *p = f2bf(v); }

template <typename OutT, int WM, int WN>
__global__ __launch_bounds__(256) void gemm_bt(const u16* __restrict__ A,
                                               const u16* __restrict__ Bw,
                                               OutT* __restrict__ C, int N, int K) {
  __shared__ u16 As[2][WM * 1024];
  __shared__ u16 Bs[2][WN * 1024];
  const int tid = threadIdx.x;
  const int lane = tid & 63;
  const int wave = tid >> 6;
  const int wm = wave >> 1, wn = wave & 1;
  const int lh = lane & 15, quad = lane >> 4;
  const int q8 = quad * 8;
  // XCD-chunked swizzle (T1): each XCD gets a compact W x (H/8) rectangle.
  int vbx = blockIdx.x, vby = blockIdx.y;
  if ((gridDim.y & 7) == 0) {
    const int W = gridDim.x;
    const int lin = blockIdx.y * W + blockIdx.x;   // hw x-fastest order
    const int xcd = lin & 7, slot = lin >> 3;
    vbx = slot % W;
    vby = xcd * (gridDim.y >> 3) + slot / W;
  }
  const int m0 = vby * (WM * 32), n0 = vbx * (WN * 32);
  constexpr int NCH = 2 * (WM + WN);
  constexpr int PER = NCH / 4;

  auto stage = [&](int buf, int kt) {
    const int kb = kt * 32;
#pragma unroll
    for (int i = 0; i < PER; ++i) {
      const int c = wave * PER + i;
      if (c < 2 * WM) {
        gload_lds16(A + (size_t)(m0 + c * 16 + lh) * K + kb + q8,
                    &As[buf][c * 512 + lane * 8]);
      } else {
        const int rb = c - 2 * WM;
        gload_lds16(Bw + (size_t)(n0 + rb * 16 + lh) * K + kb + q8,
                    &Bs[buf][rb * 512 + lane * 8]);
      }
    }
  };

  f32x4 acc[WM][WN];
#pragma unroll
  for (int i = 0; i < WM; ++i)
#pragma unroll
    for (int j = 0; j < WN; ++j) { acc[i][j][0] = 0.f; acc[i][j][1] = 0.f; acc[i][j][2] = 0.f; acc[i][j][3] = 0.f; }

  const int nkt = K >> 5;
  stage(0, 0);
  __syncthreads();  // drain DMA for tile 0
  for (int kt = 0; kt < nkt; ++kt) {
    const int p = kt & 1;
    if (kt < nkt - 1) stage(1 - p, kt + 1);  // prefetch; drained at the end barrier
    s16x8 af[WM], bf4[WN];
#pragma unroll
    for (int mb = 0; mb < WM; ++mb)
      af[mb] = *reinterpret_cast<const s16x8*>(&As[p][(wm * WM + mb) * 512 + lane * 8]);
#pragma unroll
    for (int nb = 0; nb < WN; ++nb)
      bf4[nb] = *reinterpret_cast<const s16x8*>(&Bs[p][(wn * WN + nb) * 512 + lane * 8]);
#pragma unroll
    for (int mb = 0; mb < WM; ++mb)
#pragma unroll
      for (int nb = 0; nb < WN; ++nb)
        acc[mb][nb] = __builtin_amdgcn_mfma_f32_16x16x32_bf16(af[mb], bf4[nb], acc[mb][nb], 0, 0, 0);
    __syncthreads();
  }
#pragma unroll
  for (int mb = 0; mb < WM; ++mb)
#pragma unroll
    for (int nb = 0; nb < WN; ++nb) {
      const int col = n0 + wn * (WN * 16) + nb * 16 + lh;
#pragma unroll
      for (int r = 0; r < 4; ++r) {
        const int row = m0 + wm * (WM * 16) + mb * 16 + quad * 4 + r;
        store_out(&C[(size_t)row * N + col], acc[mb][nb][r]);
      }
    }
}

// ---------------- QKV GEMM (BK=32, dbuf) + fused RoPE + V-transpose, XCD swizzle ----------------
__global__ __launch_bounds__(256) void qkv_gemm(const u16* __restrict__ A,
                                                const u16* __restrict__ Bw,
                                                u16* __restrict__ Vt,
                                                u16* __restrict__ Qs,
                                                u16* __restrict__ Kb,
                                                u16* __restrict__ K2b) {
  __shared__ u16 As[2][4096];
  __shared__ u16 Bs[2][4096];
  const int tid = threadIdx.x;
  const int lane = tid & 63;
  const int wave = tid >> 6;
  const int wm = wave >> 1, wn = wave & 1;
  const int lh = lane & 15, quad = lane >> 4;
  const int q8 = quad * 8;
  // XCD-chunked swizzle: 768 blocks = 8 XCDs x (24 bx x 4 by).
  const int lin = blockIdx.y * 24 + blockIdx.x;   // hw x-fastest order
  const int xcd = lin & 7, slot = lin >> 3;       // slot 0..95
  const int bx = slot % 24;
  const int vby = xcd * 4 + slot / 24;
  const int m0 = vby * 128, n0 = bx * 128;
  const int K = 1024;

  auto stage = [&](int buf, int kt) {
    const int kb = kt * 32;
#pragma unroll
    for (int i = 0; i < 4; ++i) {
      const int c = wave * 4 + i;  // 0..15: 0-7 A chunks, 8-15 B chunks
      if (c < 8) {
        gload_lds16(A + (size_t)(m0 + c * 16 + lh) * K + kb + q8,
                    &As[buf][c * 512 + lane * 8]);
      } else {
        const int rb = c - 8;
        gload_lds16(Bw + (size_t)(n0 + rb * 16 + lh) * K + kb + q8,
                    &Bs[buf][rb * 512 + lane * 8]);
      }
    }
  };

  f32x4 acc[4][4];
#pragma unroll
  for (int i = 0; i < 4; ++i)
#pragma unroll
    for (int j = 0; j < 4; ++j) { acc[i][j][0] = 0.f; acc[i][j][1] = 0.f; acc[i][j][2] = 0.f; acc[i][j][3] = 0.f; }

  stage(0, 0);
  __syncthreads();
  for (int kt = 0; kt < 32; ++kt) {
    const int p = kt & 1;
    if (kt < 31) stage(1 - p, kt + 1);
    s16x8 af[4], bf4[4];
#pragma unroll
    for (int mb = 0; mb < 4; ++mb)
      af[mb] = *reinterpret_cast<const s16x8*>(&As[p][(wm * 4 + mb) * 512 + lane * 8]);
#pragma unroll
    for (int nb = 0; nb < 4; ++nb)
      bf4[nb] = *reinterpret_cast<const s16x8*>(&Bs[p][(wn * 4 + nb) * 512 + lane * 8]);
#pragma unroll
    for (int mb = 0; mb < 4; ++mb)
#pragma unroll
      for (int nb = 0; nb < 4; ++nb)
        acc[mb][nb] = __builtin_amdgcn_mfma_f32_16x16x32_bf16(af[mb], bf4[nb], acc[mb][nb], 0, 0, 0);
    __syncthreads();
  }

  if (bx < 16) {
    const bool isQ = (bx < 8);
#pragma unroll
    for (int nb = 0; nb < 2; ++nb) {
      const int d = nb * 16 + lh;                       // 0..31 (first half of head)
      const float invf = __expf((float)d * -0.2878231366f);  // 10000^(-d/32)
      const int col = n0 + wn * 64 + nb * 16 + lh;
      const int ch = col & 1023;                        // col within Q or K block
      const int h = ch >> 6;
#pragma unroll
      for (int mb = 0; mb < 4; ++mb)
#pragma unroll
        for (int r = 0; r < 4; ++r) {
          const int row = m0 + wm * 64 + mb * 16 + quad * 4 + r;
          const int s = row & 2047, b = row >> 11;
          float ang = (float)s * invf;
          float sv, cv;
          __sincosf(ang, &sv, &cv);
          const float v1 = acc[mb][nb][r], v2 = acc[mb][nb + 2][r];
          const float e0 = v1 * cv - v2 * sv;
          const float e1 = v2 * cv + v1 * sv;
          const size_t ofs = (size_t)((b * 16 + h) * 2048 + s) * 64 + d;
          if (isQ) {
            Qs[ofs]      = f2bf(e0 * 0.125f);
            Qs[ofs + 32] = f2bf(e1 * 0.125f);
          } else {
            Kb[ofs]       = f2bf(e0);
            Kb[ofs + 32]  = f2bf(e1);
            K2b[ofs]      = f2bf(e0 * e0);
            K2b[ofs + 32] = f2bf(e1 * e1);
          }
        }
    }
  } else {
    // V: direct transposed store. col -> (h, d); rows r are 4 consecutive s.
#pragma unroll
    for (int mb = 0; mb < 4; ++mb)
#pragma unroll
      for (int nb = 0; nb < 4; ++nb) {
        const int col = n0 + wn * 64 + nb * 16 + lh;
        const int ch = col & 1023;
        const int h = ch >> 6, d = ch & 63;
        const int row0 = m0 + wm * 64 + mb * 16 + quad * 4;
        const int s0 = row0 & 2047, b = row0 >> 11;
        u16x4 o;
#pragma unroll
        for (int r = 0; r < 4; ++r) o[r] = f2bf(acc[mb][nb][r]);
        *reinterpret_cast<u16x4*>(Vt + (size_t)((b * 16 + h) * 64 + d) * 2048 + s0) = o;
      }
  }
}

// ---------------- flash-style causal amplified attention, KVBLK=32, SWAPPED QK^T ----------------
// S computed as mfma(K, Q) -> S[key=row][query=col]: each lane holds, for query lh,
// keys {4q..4q+3} U {16+4q..16+4q+3} (q=quad) -- which IS an A-operand fragment under
// a permuted k-order. MFMA's k-sum is permutation-invariant, so V is loaded with the
// SAME permutation (two b64 loads per d-block) and exp results pack DIRECTLY into the
// PV A-operand registers: no Pbuf, no LDS round-trip, no shuffles in the P path.
// PV output layout (row=query, col=d) is identical to before -> epilogue unchanged.
// LDS = stageS only (16 KB). lsum is per-lane scalar per query-block, reduced once
// at the end via shfl_xor(16/32).
__global__ __launch_bounds__(256, 2) void attn_kernel(const u16* __restrict__ Qs,
                                                      const u16* __restrict__ Kb,
                                                      const u16* __restrict__ K2b,
                                                      const u16* __restrict__ Vt,
                                                      const float* __restrict__ gate,
                                                      u16* __restrict__ attn,
                                                      float* __restrict__ Opart,
                                                      float* __restrict__ Lpart,
                                                      float* __restrict__ Opart2,
                                                      float* __restrict__ Lpart2) {
  const int lin = blockIdx.y * 44 + blockIdx.x;
  const int xcd = lin & 7;
  const int slot = lin >> 3;          // 0..175
  const int bh = xcd * 4 + (slot / 44);
  const int bxv = slot % 44;

  int qi, kt0, kt1, chunk, which;
  bool split;
  if (bxv < 32) {
    qi = 15 - (bxv >> 2); chunk = bxv & 3; split = true; which = 0;
    const int T = 4 * qi + 4;                     // total key tiles (32-wide)
    kt0 = (chunk * T) >> 2;
    kt1 = (((chunk + 1) * T) >> 2) - 1;
  } else if (bxv < 40) {
    const int t = bxv - 32;
    qi = 7 - (t >> 1); chunk = t & 1; split = true; which = 1;
    const int nk = 2 * qi + 2; kt0 = chunk * nk; kt1 = kt0 + nk - 1;
  } else {
    qi = 43 - bxv; split = false; which = 0; chunk = 0; kt0 = 0; kt1 = 4 * qi + 3;
  }
  const int tid = threadIdx.x, lane = tid & 63, wave = tid >> 6;
  const int lh = lane & 15, quad = lane >> 4;
  const int b = bh >> 4, h = bh & 15;
  __shared__ u16 stageS[2][4096];   // [K chunks: 0..2047 | K2 chunks: 2048..4095]
  const int base = qi * 128 + wave * 32;   // wave's first Q row
  const int q8 = quad * 8;

  auto do_stage = [&](int buf, int kt) {
#pragma unroll
    for (int i = 0; i < 2; ++i) {
      const int c = wave * 2 + i;   // 0..7; t2=c>>2 (0=K,1=K2), f=c&3 = kk*2+kb
      const int t2 = c >> 2, f = c & 3, kk = f >> 1, kb2 = f & 1;
      const u16* src = (t2 ? K2b : Kb) +
          (size_t)(bh * 2048 + kt * 32 + kb2 * 16 + lh) * 64 + kk * 32 + q8;
      gload_lds16(src, &stageS[buf][t2 * 2048 + f * 512 + lane * 8]);
    }
  };

  // Q fragments (B-operand now; same per-lane layout): n = lh, k = kk*32 + quad*8 + j.
  s16x8 qf[2][2], q2f[2][2];
#pragma unroll
  for (int qb = 0; qb < 2; ++qb) {
    const size_t qoff = (size_t)(bh * 2048 + base + qb * 16 + lh) * 64 + q8;
#pragma unroll
    for (int kk = 0; kk < 2; ++kk) {
      qf[qb][kk] = *reinterpret_cast<const s16x8*>(Qs + qoff + kk * 32);
#pragma unroll
      for (int j = 0; j < 8; ++j) {
        float f = bf2f((u16)qf[qb][kk][j]);
        q2f[qb][kk][j] = (short)f2bf(f * f * 0.8f);
      }
    }
  }

  const u16* Vbase = Vt + (size_t)bh * 131072;

  f32x4 oacc[2][4];   // [qb][d-block]: row=query(quad*4+r), col=d(lh) -- same as before
  float lsum[2];      // per-lane partial row sum for query qb*16+lh
#pragma unroll
  for (int qb = 0; qb < 2; ++qb) {
#pragma unroll
    for (int nb = 0; nb < 4; ++nb) { oacc[qb][nb][0] = 0.f; oacc[qb][nb][1] = 0.f; oacc[qb][nb][2] = 0.f; oacc[qb][nb][3] = 0.f; }
    lsum[qb] = 0.f;
  }

  do_stage(0, kt0);
  __syncthreads();  // drain DMA for first tile

  const int wmaxrow = base + 31;
  for (int kt = kt0; kt <= kt1; ++kt) {
    const int p = (kt - kt0) & 1;
    if (kt < kt1) do_stage(1 - p, kt + 1);  // async prefetch, drained at end barrier

    if (kt * 32 <= wmaxrow) {  // wave-uniform skip of fully-masked tiles
      const u16* Ks = stageS[p];
      f32x4 sacc[2][2];   // [kb][qb]: row=key(quad*4+r), col=query(lh)
#pragma unroll
      for (int kb = 0; kb < 2; ++kb)
#pragma unroll
        for (int qb = 0; qb < 2; ++qb) { sacc[kb][qb][0] = -8.f; sacc[kb][qb][1] = -8.f; sacc[kb][qb][2] = -8.f; sacc[kb][qb][3] = -8.f; }
      __builtin_amdgcn_s_setprio(1);
#pragma unroll
      for (int kb = 0; kb < 2; ++kb)
#pragma unroll
        for (int kk = 0; kk < 2; ++kk) {
          s16x8 kf  = *reinterpret_cast<const s16x8*>(&Ks[(kk * 2 + kb) * 512 + lane * 8]);
          s16x8 k2f = *reinterpret_cast<const s16x8*>(&Ks[2048 + (kk * 2 + kb) * 512 + lane * 8]);
#pragma unroll
          for (int qb = 0; qb < 2; ++qb) {
            sacc[kb][qb] = __builtin_amdgcn_mfma_f32_16x16x32_bf16(kf,  qf[qb][kk],  sacc[kb][qb], 0, 0, 0);
            sacc[kb][qb] = __builtin_amdgcn_mfma_f32_16x16x32_bf16(k2f, q2f[qb][kk], sacc[kb][qb], 0, 0, 0);
          }
        }
      __builtin_amdgcn_s_setprio(0);

      // V fragments, k-permuted to match the lane-local P order:
      // slot j<4 -> key quad*4+j ; j>=4 -> key 16+quad*4+(j-4). Two b64 loads per d-block.
      s16x8 vf[4];
#pragma unroll
      for (int nb = 0; nb < 4; ++nb) {
        const u16* vrow = Vbase + (size_t)(nb * 16 + lh) * 2048 + kt * 32 + quad * 4;
        s16x4 lo = *reinterpret_cast<const s16x4*>(vrow);
        s16x4 hi = *reinterpret_cast<const s16x4*>(vrow + 16);
        vf[nb][0] = lo[0]; vf[nb][1] = lo[1]; vf[nb][2] = lo[2]; vf[nb][3] = lo[3];
        vf[nb][4] = hi[0]; vf[nb][5] = hi[1]; vf[nb][6] = hi[2]; vf[nb][7] = hi[3];
      }

      if (kt * 32 + 31 > base) {  // tiles overlapping the diagonal: elementwise mask
#pragma unroll
        for (int kb = 0; kb < 2; ++kb)
#pragma unroll
          for (int qb = 0; qb < 2; ++qb) {
            const int queryg = base + qb * 16 + lh;
#pragma unroll
            for (int r = 0; r < 4; ++r) {
              const int keyg = kt * 32 + kb * 16 + quad * 4 + r;
              if (keyg > queryg) sacc[kb][qb][r] = -1e9f;
            }
          }
      }
      // p = exp(s - 8): packs DIRECTLY into PV A-operand (lane-local, no LDS)
      s16x8 pa[2];
#pragma unroll
      for (int qb = 0; qb < 2; ++qb)
#pragma unroll
        for (int kb = 0; kb < 2; ++kb)
#pragma unroll
          for (int r = 0; r < 4; ++r) {
            float pv = __expf(sacc[kb][qb][r]);
            lsum[qb] += pv;
            pa[qb][kb * 4 + r] = (short)f2bf(pv);
          }
      // PV: one k=32 MFMA per (qb, d-block), all operands in registers
      __builtin_amdgcn_s_setprio(1);
#pragma unroll
      for (int qb = 0; qb < 2; ++qb)
#pragma unroll
        for (int nb = 0; nb < 4; ++nb)
          oacc[qb][nb] = __builtin_amdgcn_mfma_f32_16x16x32_bf16(pa[qb], vf[nb], oacc[qb][nb], 0, 0, 0);
      __builtin_amdgcn_s_setprio(0);
    }
    __syncthreads();  // all waves done with stageS[p]; prefetch for kt+1 drained
  }
  // reduce row sums across the 4 quads holding each query (lanes lh, lh+16, lh+32, lh+48)
#pragma unroll
  for (int qb = 0; qb < 2; ++qb) {
    float rs = lsum[qb];
    rs += __shfl_xor(rs, 16);
    rs += __shfl_xor(rs, 32);
    lsum[qb] = rs;   // uniform across quads for fixed lh: sum for query qb*16+lh
  }
  if (split) {
    // unnormalized partials to ws (fp32)
#pragma unroll
    for (int qb = 0; qb < 2; ++qb)
#pragma unroll
      for (int r = 0; r < 4; ++r) {
        const float lq = __shfl(lsum[qb], quad * 4 + r);   // sum for query quad*4+r
        const int rowg = base + qb * 16 + quad * 4 + r;
        if (which == 0) {
          const size_t orow = (size_t)chunk * 32768 + bh * 1024 + (rowg - 1024);
          if (lh == 0) Lpart[orow] = lq;
#pragma unroll
          for (int nb = 0; nb < 4; ++nb)
            Opart[orow * 64 + nb * 16 + lh] = oacc[qb][nb][r];
        } else {
          const size_t orow = (size_t)chunk * 16384 + bh * 512 + (rowg - 512);
          if (lh == 0) Lpart2[orow] = lq;
#pragma unroll
          for (int nb = 0; nb < 4; ++nb)
            Opart2[orow * 64 + nb * 16 + lh] = oacc[qb][nb][r];
        }
      }
  } else {
    // finalize: o/l, epilogue o + 0.05*o^2*g[d] (out2==out1 identity)
#pragma unroll
    for (int qb = 0; qb < 2; ++qb)
#pragma unroll
      for (int r = 0; r < 4; ++r) {
        const float lq = __shfl(lsum[qb], quad * 4 + r);
        const float invl = 1.0f / lq;
        const int rows = base + qb * 16 + quad * 4 + r;
#pragma unroll
        for (int nb = 0; nb < 4; ++nb) {
          float o = oacc[qb][nb][r] * invl;
          float val = o + 0.05f * o * o * gate[nb * 16 + lh];
          attn[(size_t)(b * 2048 + rows) * 1024 + h * 64 + nb * 16 + lh] = f2bf(val);
        }
      }
  }
}

// ---------------- combine split-K partials (rows 512..2047) ----------------
__global__ __launch_bounds__(256) void combine_kernel(const float* __restrict__ Opart,
                                                      const float* __restrict__ Lpart,
                                                      const float* __restrict__ Opart2,
                                                      const float* __restrict__ Lpart2,
                                                      const float* __restrict__ gate,
                                                      u16* __restrict__ attn) {
  int idx = blockIdx.x * 256 + threadIdx.x;   // 0 .. 3145727
  int d = idx & 63;
  int r_all = idx >> 6;
  float o, l;
  int bh, s;
  if (r_all < 32768) {            // rows s >= 1024 (qi >= 8): 4 chunks
    o = Opart[idx] + Opart[idx + 2097152] + Opart[idx + 4194304] + Opart[idx + 6291456];
    l = Lpart[r_all] + Lpart[r_all + 32768] + Lpart[r_all + 65536] + Lpart[r_all + 98304];
    bh = r_all >> 10; s = 1024 + (r_all & 1023);
  } else {                        // rows 512..1023 (qi 4..7): 2 chunks
    const int r2 = r_all - 32768;
    const int i2 = idx - 2097152;
    o = Opart2[i2] + Opart2[i2 + 1048576];
    l = Lpart2[r2] + Lpart2[r2 + 16384];
    bh = r2 >> 9; s = 512 + (r2 & 511);
  }
  o /= l;
  float val = o + 0.05f * o * o * gate[d];
  int b = bh >> 4, h = bh & 15;
  attn[(size_t)(b * 2048 + s) * 1024 + h * 64 + d] = f2bf(val);
}

extern "C" void kernel_launch(void* const* d_in, const int* in_sizes, int n_in,
                              void* d_out, int out_size, void* d_ws, size_t ws_size,
                              hipStream_t stream) {
  (void)in_sizes; (void)n_in; (void)out_size; (void)ws_size;
  const float* x    = (const float*)d_in[0];
  const float* Wq   = (const float*)d_in[1];
  const float* Wk   = (const float*)d_in[2];
  const float* Wv   = (const float*)d_in[3];
  const float* Wo   = (const float*)d_in[4];
  const float* gate = (const float*)d_in[5];

  u16* ws    = (u16*)d_ws;
  u16* xbf   = ws;                    // 4096x1024 bf16 (qkv A input; attn out aliases later)
  u16* wbf   = xbf + 4194304;         // 3072x1024 (Wq|Wk|Wv rows)
  u16* wobf  = wbf + 3145728;         // 1024x1024
  u16* Qsb   = wobf + 1048576;        // (B,H,S,64) q/8
  u16* Kbb   = Qsb + 4194304;         // (B,H,S,64)
  u16* K2bb  = Kbb + 4194304;         // (B,H,S,64)
  u16* Vtb   = K2bb + 4194304;        // (B,H,64,S)  (written directly by qkv epilogue)
  float* Opart  = (float*)(Vtb + 4194304); // 4 x 32 x 1024 x 64 fp32 (33.6 MB)
  float* Lpart  = Opart + 8388608;         // 4 x 32 x 1024 fp32
  float* Opart2 = Lpart + 131072;          // 2 x 32 x 512 x 64 fp32 (8.4 MB)
  float* Lpart2 = Opart2 + 2097152;        // 2 x 32 x 512 fp32
  u16* attnb = xbf;                   // alias: attn out (xbf dead after qkv_gemm)

  cvt_all<<<8192, 256, 0, stream>>>(x, Wq, Wk, Wv, Wo, xbf, wbf, wobf);
  qkv_gemm<<<dim3(24, 32), 256, 0, stream>>>(xbf, wbf, Vtb, Qsb, Kbb, K2bb);
  attn_kernel<<<dim3(44, 32), 256, 0, stream>>>(Qsb, Kbb, K2bb, Vtb, gate, attnb,
                                                Opart, Lpart, Opart2, Lpart2);
  combine_kernel<<<12288, 256, 0, stream>>>(Opart, Lpart, Opart2, Lpart2, gate, attnb);
  gemm_bt<float, 4, 2><<<dim3(16, 32), 256, 0, stream>>>(attnb, wobf, (float*)d_out, 1024, 1024);
}

// Round 9
// 277.644 us; speedup vs baseline: 1.0050x; 1.0050x over previous
//
#include <hip/hip_runtime.h>

typedef unsigned short u16;
typedef __attribute__((ext_vector_type(4))) unsigned short u16x4;
typedef __attribute__((ext_vector_type(8))) unsigned short u16x8;
typedef __attribute__((ext_vector_type(4))) short s16x4;
typedef __attribute__((ext_vector_type(8))) short s16x8;
typedef __attribute__((ext_vector_type(4))) float f32x4;

__device__ __forceinline__ u16 f2bf(float f) {
  unsigned int u = __float_as_uint(f);
  u += 0x7FFFu + ((u >> 16) & 1u);   // RNE
  return (u16)(u >> 16);
}
__device__ __forceinline__ float bf2f(u16 h) {
  return __uint_as_float(((unsigned int)h) << 16);
}

// async global->LDS, 16B per lane; base = lane0's lds ptr, lane i writes base+i*16B.
__device__ __forceinline__ void gload_lds16(const u16* g, u16* l) {
  __builtin_amdgcn_global_load_lds(
      (const __attribute__((address_space(1))) unsigned int*)(g),
      (__attribute__((address_space(3))) unsigned int*)(l), 16, 0, 0);
}

// ---------------- fused fp32 -> bf16 convert: x + all four weights ----------------
__global__ __launch_bounds__(256) void cvt_all(const float* __restrict__ x,
                                               const float* __restrict__ Wq,
                                               const float* __restrict__ Wk,
                                               const float* __restrict__ Wv,
                                               const float* __restrict__ Wo,
                                               u16* __restrict__ xbf,
                                               u16* __restrict__ wbf,
                                               u16* __restrict__ wobf) {
  int blk = blockIdx.x;                // 0..8191
  const float* src;
  u16* dst;
  int i;
  if (blk < 4096) {
    src = x; dst = xbf; i = blk * 256 + threadIdx.x;
  } else {
    int wb = blk - 4096;               // 0..4095
    int sel = wb >> 10;
    src = (sel == 0) ? Wq : (sel == 1) ? Wk : (sel == 2) ? Wv : Wo;
    dst = (sel < 3) ? (wbf + (size_t)sel * 1048576) : wobf;
    i = (wb & 1023) * 256 + threadIdx.x;
  }
  float4 v = reinterpret_cast<const float4*>(src)[i];
  u16x4 o;
  o.x = f2bf(v.x); o.y = f2bf(v.y); o.z = f2bf(v.z); o.w = f2bf(v.w);
  reinterpret_cast<u16x4*>(dst)[i] = o;
}

// ---------------- templated GEMM, BK=32, double-buffered, XCD-chunked swizzle ----------------
__device__ __forceinline__ void store_out(float* p, float v) { *p = v; }
__device__ __forceinline__ void store_out(u16* p, float v) { *p = f2bf(v); }

template <typename OutT, int WM, int WN>
__global__ __launch_bounds__(256) void gemm_bt(const u16* __restrict__ A,
                                               const u16* __restrict__ Bw,
                                               OutT* __restrict__ C, int N, int K) {
  __shared__ u16 As[2][WM * 1024];
  __shared__ u16 Bs[2][WN * 1024];
  const int tid = threadIdx.x;
  const int lane = tid & 63;
  const int wave = tid >> 6;
  const int wm = wave >> 1, wn = wave & 1;
  const int lh = lane & 15, quad = lane >> 4;
  const int q8 = quad * 8;
  // XCD-chunked swizzle (T1): each XCD gets a compact W x (H/8) rectangle.
  int vbx = blockIdx.x, vby = blockIdx.y;
  if ((gridDim.y & 7) == 0) {
    const int W = gridDim.x;
    const int lin = blockIdx.y * W + blockIdx.x;   // hw x-fastest order
    const int xcd = lin & 7, slot = lin >> 3;
    vbx = slot % W;
    vby = xcd * (gridDim.y >> 3) + slot / W;
  }
  const int m0 = vby * (WM * 32), n0 = vbx * (WN * 32);
  constexpr int NCH = 2 * (WM + WN);
  constexpr int PER = NCH / 4;

  auto stage = [&](int buf, int kt) {
    const int kb = kt * 32;
#pragma unroll
    for (int i = 0; i < PER; ++i) {
      const int c = wave * PER + i;
      if (c < 2 * WM) {
        gload_lds16(A + (size_t)(m0 + c * 16 + lh) * K + kb + q8,
                    &As[buf][c * 512 + lane * 8]);
      } else {
        const int rb = c - 2 * WM;
        gload_lds16(Bw + (size_t)(n0 + rb * 16 + lh) * K + kb + q8,
                    &Bs[buf][rb * 512 + lane * 8]);
      }
    }
  };

  f32x4 acc[WM][WN];
#pragma unroll
  for (int i = 0; i < WM; ++i)
#pragma unroll
    for (int j = 0; j < WN; ++j) { acc[i][j][0] = 0.f; acc[i][j][1] = 0.f; acc[i][j][2] = 0.f; acc[i][j][3] = 0.f; }

  const int nkt = K >> 5;
  stage(0, 0);
  __syncthreads();  // drain DMA for tile 0
  for (int kt = 0; kt < nkt; ++kt) {
    const int p = kt & 1;
    if (kt < nkt - 1) stage(1 - p, kt + 1);  // prefetch; drained at the end barrier
    s16x8 af[WM], bf4[WN];
#pragma unroll
    for (int mb = 0; mb < WM; ++mb)
      af[mb] = *reinterpret_cast<const s16x8*>(&As[p][(wm * WM + mb) * 512 + lane * 8]);
#pragma unroll
    for (int nb = 0; nb < WN; ++nb)
      bf4[nb] = *reinterpret_cast<const s16x8*>(&Bs[p][(wn * WN + nb) * 512 + lane * 8]);
#pragma unroll
    for (int mb = 0; mb < WM; ++mb)
#pragma unroll
      for (int nb = 0; nb < WN; ++nb)
        acc[mb][nb] = __builtin_amdgcn_mfma_f32_16x16x32_bf16(af[mb], bf4[nb], acc[mb][nb], 0, 0, 0);
    __syncthreads();
  }
#pragma unroll
  for (int mb = 0; mb < WM; ++mb)
#pragma unroll
    for (int nb = 0; nb < WN; ++nb) {
      const int col = n0 + wn * (WN * 16) + nb * 16 + lh;
#pragma unroll
      for (int r = 0; r < 4; ++r) {
        const int row = m0 + wm * (WM * 16) + mb * 16 + quad * 4 + r;
        store_out(&C[(size_t)row * N + col], acc[mb][nb][r]);
      }
    }
}

// ---------------- QKV GEMM (BK=32, dbuf) + fused RoPE + V-transpose, XCD swizzle ----------------
__global__ __launch_bounds__(256) void qkv_gemm(const u16* __restrict__ A,
                                                const u16* __restrict__ Bw,
                                                u16* __restrict__ Vt,
                                                u16* __restrict__ Qs,
                                                u16* __restrict__ Kb,
                                                u16* __restrict__ K2b) {
  __shared__ u16 As[2][4096];
  __shared__ u16 Bs[2][4096];
  const int tid = threadIdx.x;
  const int lane = tid & 63;
  const int wave = tid >> 6;
  const int wm = wave >> 1, wn = wave & 1;
  const int lh = lane & 15, quad = lane >> 4;
  const int q8 = quad * 8;
  // XCD-chunked swizzle: 768 blocks = 8 XCDs x (24 bx x 4 by).
  const int lin = blockIdx.y * 24 + blockIdx.x;   // hw x-fastest order
  const int xcd = lin & 7, slot = lin >> 3;       // slot 0..95
  const int bx = slot % 24;
  const int vby = xcd * 4 + slot / 24;
  const int m0 = vby * 128, n0 = bx * 128;
  const int K = 1024;

  auto stage = [&](int buf, int kt) {
    const int kb = kt * 32;
#pragma unroll
    for (int i = 0; i < 4; ++i) {
      const int c = wave * 4 + i;  // 0..15: 0-7 A chunks, 8-15 B chunks
      if (c < 8) {
        gload_lds16(A + (size_t)(m0 + c * 16 + lh) * K + kb + q8,
                    &As[buf][c * 512 + lane * 8]);
      } else {
        const int rb = c - 8;
        gload_lds16(Bw + (size_t)(n0 + rb * 16 + lh) * K + kb + q8,
                    &Bs[buf][rb * 512 + lane * 8]);
      }
    }
  };

  f32x4 acc[4][4];
#pragma unroll
  for (int i = 0; i < 4; ++i)
#pragma unroll
    for (int j = 0; j < 4; ++j) { acc[i][j][0] = 0.f; acc[i][j][1] = 0.f; acc[i][j][2] = 0.f; acc[i][j][3] = 0.f; }

  stage(0, 0);
  __syncthreads();
  for (int kt = 0; kt < 32; ++kt) {
    const int p = kt & 1;
    if (kt < 31) stage(1 - p, kt + 1);
    s16x8 af[4], bf4[4];
#pragma unroll
    for (int mb = 0; mb < 4; ++mb)
      af[mb] = *reinterpret_cast<const s16x8*>(&As[p][(wm * 4 + mb) * 512 + lane * 8]);
#pragma unroll
    for (int nb = 0; nb < 4; ++nb)
      bf4[nb] = *reinterpret_cast<const s16x8*>(&Bs[p][(wn * 4 + nb) * 512 + lane * 8]);
#pragma unroll
    for (int mb = 0; mb < 4; ++mb)
#pragma unroll
      for (int nb = 0; nb < 4; ++nb)
        acc[mb][nb] = __builtin_amdgcn_mfma_f32_16x16x32_bf16(af[mb], bf4[nb], acc[mb][nb], 0, 0, 0);
    __syncthreads();
  }

  if (bx < 16) {
    const bool isQ = (bx < 8);
#pragma unroll
    for (int nb = 0; nb < 2; ++nb) {
      const int d = nb * 16 + lh;                       // 0..31 (first half of head)
      const float invf = __expf((float)d * -0.2878231366f);  // 10000^(-d/32)
      const int col = n0 + wn * 64 + nb * 16 + lh;
      const int ch = col & 1023;                        // col within Q or K block
      const int h = ch >> 6;
#pragma unroll
      for (int mb = 0; mb < 4; ++mb)
#pragma unroll
        for (int r = 0; r < 4; ++r) {
          const int row = m0 + wm * 64 + mb * 16 + quad * 4 + r;
          const int s = row & 2047, b = row >> 11;
          float ang = (float)s * invf;
          float sv, cv;
          __sincosf(ang, &sv, &cv);
          const float v1 = acc[mb][nb][r], v2 = acc[mb][nb + 2][r];
          const float e0 = v1 * cv - v2 * sv;
          const float e1 = v2 * cv + v1 * sv;
          const size_t ofs = (size_t)((b * 16 + h) * 2048 + s) * 64 + d;
          if (isQ) {
            Qs[ofs]      = f2bf(e0 * 0.125f);
            Qs[ofs + 32] = f2bf(e1 * 0.125f);
          } else {
            Kb[ofs]       = f2bf(e0);
            Kb[ofs + 32]  = f2bf(e1);
            K2b[ofs]      = f2bf(e0 * e0);
            K2b[ofs + 32] = f2bf(e1 * e1);
          }
        }
    }
  } else {
    // V: direct transposed store. col -> (h, d); rows r are 4 consecutive s.
#pragma unroll
    for (int mb = 0; mb < 4; ++mb)
#pragma unroll
      for (int nb = 0; nb < 4; ++nb) {
        const int col = n0 + wn * 64 + nb * 16 + lh;
        const int ch = col & 1023;
        const int h = ch >> 6, d = ch & 63;
        const int row0 = m0 + wm * 64 + mb * 16 + quad * 4;
        const int s0 = row0 & 2047, b = row0 >> 11;
        u16x4 o;
#pragma unroll
        for (int r = 0; r < 4; ++r) o[r] = f2bf(acc[mb][nb][r]);
        *reinterpret_cast<u16x4*>(Vt + (size_t)((b * 16 + h) * 64 + d) * 2048 + s0) = o;
      }
  }
}

// ---------------- flash-style causal amplified attention ----------------
// KVBLK=32, SWAPPED QK^T (round 8: lane-local P, bank-conflicts = 0) + CROSS-TILE
// REGISTER PIPELINE (round 6's winning overlap, now LDS-free): PV(t-1) runs inside
// iteration t right after QK(t)'s MFMAs -- pa/vf of t-1 are register-resident, so
// exp(t)->pack feeds NEXT iteration's PV (off the critical path) and V(t)'s b64
// loads get a full iteration + barrier to land. lsum per-kb for add-chain ILP.
// LDS = stageS only (16 KB).
__global__ __launch_bounds__(256, 2) void attn_kernel(const u16* __restrict__ Qs,
                                                      const u16* __restrict__ Kb,
                                                      const u16* __restrict__ K2b,
                                                      const u16* __restrict__ Vt,
                                                      const float* __restrict__ gate,
                                                      u16* __restrict__ attn,
                                                      float* __restrict__ Opart,
                                                      float* __restrict__ Lpart,
                                                      float* __restrict__ Opart2,
                                                      float* __restrict__ Lpart2) {
  const int lin = blockIdx.y * 44 + blockIdx.x;
  const int xcd = lin & 7;
  const int slot = lin >> 3;          // 0..175
  const int bh = xcd * 4 + (slot / 44);
  const int bxv = slot % 44;

  int qi, kt0, kt1, chunk, which;
  bool split;
  if (bxv < 32) {
    qi = 15 - (bxv >> 2); chunk = bxv & 3; split = true; which = 0;
    const int T = 4 * qi + 4;                     // total key tiles (32-wide)
    kt0 = (chunk * T) >> 2;
    kt1 = (((chunk + 1) * T) >> 2) - 1;
  } else if (bxv < 40) {
    const int t = bxv - 32;
    qi = 7 - (t >> 1); chunk = t & 1; split = true; which = 1;
    const int nk = 2 * qi + 2; kt0 = chunk * nk; kt1 = kt0 + nk - 1;
  } else {
    qi = 43 - bxv; split = false; which = 0; chunk = 0; kt0 = 0; kt1 = 4 * qi + 3;
  }
  const int tid = threadIdx.x, lane = tid & 63, wave = tid >> 6;
  const int lh = lane & 15, quad = lane >> 4;
  const int b = bh >> 4, h = bh & 15;
  __shared__ u16 stageS[2][4096];   // [K chunks: 0..2047 | K2 chunks: 2048..4095]
  const int base = qi * 128 + wave * 32;   // wave's first Q row
  const int q8 = quad * 8;

  auto do_stage = [&](int buf, int kt) {
#pragma unroll
    for (int i = 0; i < 2; ++i) {
      const int c = wave * 2 + i;   // 0..7; t2=c>>2 (0=K,1=K2), f=c&3 = kk*2+kb
      const int t2 = c >> 2, f = c & 3, kk = f >> 1, kb2 = f & 1;
      const u16* src = (t2 ? K2b : Kb) +
          (size_t)(bh * 2048 + kt * 32 + kb2 * 16 + lh) * 64 + kk * 32 + q8;
      gload_lds16(src, &stageS[buf][t2 * 2048 + f * 512 + lane * 8]);
    }
  };

  // Q fragments (B-operand now; same per-lane layout): n = lh, k = kk*32 + quad*8 + j.
  s16x8 qf[2][2], q2f[2][2];
#pragma unroll
  for (int qb = 0; qb < 2; ++qb) {
    const size_t qoff = (size_t)(bh * 2048 + base + qb * 16 + lh) * 64 + q8;
#pragma unroll
    for (int kk = 0; kk < 2; ++kk) {
      qf[qb][kk] = *reinterpret_cast<const s16x8*>(Qs + qoff + kk * 32);
#pragma unroll
      for (int j = 0; j < 8; ++j) {
        float f = bf2f((u16)qf[qb][kk][j]);
        q2f[qb][kk][j] = (short)f2bf(f * f * 0.8f);
      }
    }
  }

  const u16* Vbase = Vt + (size_t)bh * 131072;

  f32x4 oacc[2][4];    // [qb][d-block]: row=query(quad*4+r), col=d(lh)
  float lsum[2][2];    // [qb][kb] partial row sums (ILP); merged at the end
#pragma unroll
  for (int qb = 0; qb < 2; ++qb) {
#pragma unroll
    for (int nb = 0; nb < 4; ++nb) { oacc[qb][nb][0] = 0.f; oacc[qb][nb][1] = 0.f; oacc[qb][nb][2] = 0.f; oacc[qb][nb][3] = 0.f; }
    lsum[qb][0] = 0.f; lsum[qb][1] = 0.f;
  }

  do_stage(0, kt0);
  __syncthreads();  // drain DMA for first tile

  // cross-tile register pipeline state: P/V of the pending (previous) tile
  s16x8 paP[2], vfP[4];
  int pvalid = 0;

  const int wmaxrow = base + 31;
  for (int kt = kt0; kt <= kt1; ++kt) {
    const int p = (kt - kt0) & 1;
    if (kt < kt1) do_stage(1 - p, kt + 1);  // async prefetch, drained at end barrier

    if (kt * 32 <= wmaxrow) {  // wave-uniform skip of fully-masked tiles
      const u16* Ks = stageS[p];
      f32x4 sacc[2][2];   // [kb][qb]: row=key(quad*4+r), col=query(lh)
#pragma unroll
      for (int kb = 0; kb < 2; ++kb)
#pragma unroll
        for (int qb = 0; qb < 2; ++qb) { sacc[kb][qb][0] = -8.f; sacc[kb][qb][1] = -8.f; sacc[kb][qb][2] = -8.f; sacc[kb][qb][3] = -8.f; }
      __builtin_amdgcn_s_setprio(1);
#pragma unroll
      for (int kb = 0; kb < 2; ++kb)
#pragma unroll
        for (int kk = 0; kk < 2; ++kk) {
          s16x8 kf  = *reinterpret_cast<const s16x8*>(&Ks[(kk * 2 + kb) * 512 + lane * 8]);
          s16x8 k2f = *reinterpret_cast<const s16x8*>(&Ks[2048 + (kk * 2 + kb) * 512 + lane * 8]);
#pragma unroll
          for (int qb = 0; qb < 2; ++qb) {
            sacc[kb][qb] = __builtin_amdgcn_mfma_f32_16x16x32_bf16(kf,  qf[qb][kk],  sacc[kb][qb], 0, 0, 0);
            sacc[kb][qb] = __builtin_amdgcn_mfma_f32_16x16x32_bf16(k2f, q2f[qb][kk], sacc[kb][qb], 0, 0, 0);
          }
        }
      // PV of the PREVIOUS tile: operands register-resident since last iteration.
      // Its MFMAs interleave with QK's above; no dependency on this tile's exp.
      if (pvalid) {
#pragma unroll
        for (int qb = 0; qb < 2; ++qb)
#pragma unroll
          for (int nb = 0; nb < 4; ++nb)
            oacc[qb][nb] = __builtin_amdgcn_mfma_f32_16x16x32_bf16(paP[qb], vfP[nb], oacc[qb][nb], 0, 0, 0);
      }
      __builtin_amdgcn_s_setprio(0);

      // V fragments for THIS tile (k-permuted to lane-local P order); consumed next
      // iteration -> full iteration + barrier of latency hiding.
      s16x8 vfC[4];
#pragma unroll
      for (int nb = 0; nb < 4; ++nb) {
        const u16* vrow = Vbase + (size_t)(nb * 16 + lh) * 2048 + kt * 32 + quad * 4;
        s16x4 lo = *reinterpret_cast<const s16x4*>(vrow);
        s16x4 hi = *reinterpret_cast<const s16x4*>(vrow + 16);
        vfC[nb][0] = lo[0]; vfC[nb][1] = lo[1]; vfC[nb][2] = lo[2]; vfC[nb][3] = lo[3];
        vfC[nb][4] = hi[0]; vfC[nb][5] = hi[1]; vfC[nb][6] = hi[2]; vfC[nb][7] = hi[3];
      }

      if (kt * 32 + 31 > base) {  // tiles overlapping the diagonal: elementwise mask
#pragma unroll
        for (int kb = 0; kb < 2; ++kb)
#pragma unroll
          for (int qb = 0; qb < 2; ++qb) {
            const int queryg = base + qb * 16 + lh;
#pragma unroll
            for (int r = 0; r < 4; ++r) {
              const int keyg = kt * 32 + kb * 16 + quad * 4 + r;
              if (keyg > queryg) sacc[kb][qb][r] = -1e9f;
            }
          }
      }
      // p = exp(s - 8): lane-local pack into next iteration's PV A-operand
      s16x8 paC[2];
#pragma unroll
      for (int qb = 0; qb < 2; ++qb)
#pragma unroll
        for (int kb = 0; kb < 2; ++kb)
#pragma unroll
          for (int r = 0; r < 4; ++r) {
            float pv = __expf(sacc[kb][qb][r]);
            lsum[qb][kb] += pv;
            paC[qb][kb * 4 + r] = (short)f2bf(pv);
          }
      // promote to pending state (pure register renames)
#pragma unroll
      for (int qb = 0; qb < 2; ++qb) paP[qb] = paC[qb];
#pragma unroll
      for (int nb = 0; nb < 4; ++nb) vfP[nb] = vfC[nb];
      pvalid = 1;
    }
    __syncthreads();  // all waves done with stageS[p]; prefetch for kt+1 drained
  }
  // tail: PV of the last computed tile
  if (pvalid) {
#pragma unroll
    for (int qb = 0; qb < 2; ++qb)
#pragma unroll
      for (int nb = 0; nb < 4; ++nb)
        oacc[qb][nb] = __builtin_amdgcn_mfma_f32_16x16x32_bf16(paP[qb], vfP[nb], oacc[qb][nb], 0, 0, 0);
  }
  // reduce row sums: merge kb partials, then across the 4 quads (lanes lh+16k)
  float lrow[2];
#pragma unroll
  for (int qb = 0; qb < 2; ++qb) {
    float rs = lsum[qb][0] + lsum[qb][1];
    rs += __shfl_xor(rs, 16);
    rs += __shfl_xor(rs, 32);
    lrow[qb] = rs;   // sum for query qb*16+lh (uniform across quads)
  }
  if (split) {
    // unnormalized partials to ws (fp32)
#pragma unroll
    for (int qb = 0; qb < 2; ++qb)
#pragma unroll
      for (int r = 0; r < 4; ++r) {
        const float lq = __shfl(lrow[qb], quad * 4 + r);   // sum for query quad*4+r
        const int rowg = base + qb * 16 + quad * 4 + r;
        if (which == 0) {
          const size_t orow = (size_t)chunk * 32768 + bh * 1024 + (rowg - 1024);
          if (lh == 0) Lpart[orow] = lq;
#pragma unroll
          for (int nb = 0; nb < 4; ++nb)
            Opart[orow * 64 + nb * 16 + lh] = oacc[qb][nb][r];
        } else {
          const size_t orow = (size_t)chunk * 16384 + bh * 512 + (rowg - 512);
          if (lh == 0) Lpart2[orow] = lq;
#pragma unroll
          for (int nb = 0; nb < 4; ++nb)
            Opart2[orow * 64 + nb * 16 + lh] = oacc[qb][nb][r];
        }
      }
  } else {
    // finalize: o/l, epilogue o + 0.05*o^2*g[d] (out2==out1 identity)
#pragma unroll
    for (int qb = 0; qb < 2; ++qb)
#pragma unroll
      for (int r = 0; r < 4; ++r) {
        const float lq = __shfl(lrow[qb], quad * 4 + r);
        const float invl = 1.0f / lq;
        const int rows = base + qb * 16 + quad * 4 + r;
#pragma unroll
        for (int nb = 0; nb < 4; ++nb) {
          float o = oacc[qb][nb][r] * invl;
          float val = o + 0.05f * o * o * gate[nb * 16 + lh];
          attn[(size_t)(b * 2048 + rows) * 1024 + h * 64 + nb * 16 + lh] = f2bf(val);
        }
      }
  }
}

// ---------------- combine split-K partials (rows 512..2047) ----------------
__global__ __launch_bounds__(256) void combine_kernel(const float* __restrict__ Opart,
                                                      const float* __restrict__ Lpart,
                                                      const float* __restrict__ Opart2,
                                                      const float* __restrict__ Lpart2,
                                                      const float* __restrict__ gate,
                                                      u16* __restrict__ attn) {
  int idx = blockIdx.x * 256 + threadIdx.x;   // 0 .. 3145727
  int d = idx & 63;
  int r_all = idx >> 6;
  float o, l;
  int bh, s;
  if (r_all < 32768) {            // rows s >= 1024 (qi >= 8): 4 chunks
    o = Opart[idx] + Opart[idx + 2097152] + Opart[idx + 4194304] + Opart[idx + 6291456];
    l = Lpart[r_all] + Lpart[r_all + 32768] + Lpart[r_all + 65536] + Lpart[r_all + 98304];
    bh = r_all >> 10; s = 1024 + (r_all & 1023);
  } else {                        // rows 512..1023 (qi 4..7): 2 chunks
    const int r2 = r_all - 32768;
    const int i2 = idx - 2097152;
    o = Opart2[i2] + Opart2[i2 + 1048576];
    l = Lpart2[r2] + Lpart2[r2 + 16384];
    bh = r2 >> 9; s = 512 + (r2 & 511);
  }
  o /= l;
  float val = o + 0.05f * o * o * gate[d];
  int b = bh >> 4, h = bh & 15;
  attn[(size_t)(b * 2048 + s) * 1024 + h * 64 + d] = f2bf(val);
}

extern "C" void kernel_launch(void* const* d_in, const int* in_sizes, int n_in,
                              void* d_out, int out_size, void* d_ws, size_t ws_size,
                              hipStream_t stream) {
  (void)in_sizes; (void)n_in; (void)out_size; (void)ws_size;
  const float* x    = (const float*)d_in[0];
  const float* Wq   = (const float*)d_in[1];
  const float* Wk   = (const float*)d_in[2];
  const float* Wv   = (const float*)d_in[3];
  const float* Wo   = (const float*)d_in[4];
  const float* gate = (const float*)d_in[5];

  u16* ws    = (u16*)d_ws;
  u16* xbf   = ws;                    // 4096x1024 bf16 (qkv A input; attn out aliases later)
  u16* wbf   = xbf + 4194304;         // 3072x1024 (Wq|Wk|Wv rows)
  u16* wobf  = wbf + 3145728;         // 1024x1024
  u16* Qsb   = wobf + 1048576;        // (B,H,S,64) q/8
  u16* Kbb   = Qsb + 4194304;         // (B,H,S,64)
  u16* K2bb  = Kbb + 4194304;         // (B,H,S,64)
  u16* Vtb   = K2bb + 4194304;        // (B,H,64,S)  (written directly by qkv epilogue)
  float* Opart  = (float*)(Vtb + 4194304); // 4 x 32 x 1024 x 64 fp32 (33.6 MB)
  float* Lpart  = Opart + 8388608;         // 4 x 32 x 1024 fp32
  float* Opart2 = Lpart + 131072;          // 2 x 32 x 512 x 64 fp32 (8.4 MB)
  float* Lpart2 = Opart2 + 2097152;        // 2 x 32 x 512 fp32
  u16* attnb = xbf;                   // alias: attn out (xbf dead after qkv_gemm)

  cvt_all<<<8192, 256, 0, stream>>>(x, Wq, Wk, Wv, Wo, xbf, wbf, wobf);
  qkv_gemm<<<dim3(24, 32), 256, 0, stream>>>(xbf, wbf, Vtb, Qsb, Kbb, K2bb);
  attn_kernel<<<dim3(44, 32), 256, 0, stream>>>(Qsb, Kbb, K2bb, Vtb, gate, attnb,
                                                Opart, Lpart, Opart2, Lpart2);
  combine_kernel<<<12288, 256, 0, stream>>>(Opart, Lpart, Opart2, Lpart2, gate, attnb);
  gemm_bt<float, 4, 2><<<dim3(16, 32), 256, 0, stream>>>(attnb, wobf, (float*)d_out, 1024, 1024);
}

// Round 10
// 245.529 us; speedup vs baseline: 1.1365x; 1.1308x over previous
//
#include <hip/hip_runtime.h>

typedef unsigned short u16;
typedef __attribute__((ext_vector_type(4))) unsigned short u16x4;
typedef __attribute__((ext_vector_type(8))) unsigned short u16x8;
typedef __attribute__((ext_vector_type(8))) short s16x8;
typedef __attribute__((ext_vector_type(4))) float f32x4;

__device__ __forceinline__ u16 f2bf(float f) {
  unsigned int u = __float_as_uint(f);
  u += 0x7FFFu + ((u >> 16) & 1u);   // RNE
  return (u16)(u >> 16);
}
__device__ __forceinline__ float bf2f(u16 h) {
  return __uint_as_float(((unsigned int)h) << 16);
}

// async global->LDS, 16B per lane; base = lane0's lds ptr, lane i writes base+i*16B.
__device__ __forceinline__ void gload_lds16(const u16* g, u16* l) {
  __builtin_amdgcn_global_load_lds(
      (const __attribute__((address_space(1))) unsigned int*)(g),
      (__attribute__((address_space(3))) unsigned int*)(l), 16, 0, 0);
}

// ---------------- fused fp32 -> bf16 convert: x + weights + RoPE cos/sin table ----------------
// blk < 4096: x. 4096..8191: weights. >= 8192 (256 blocks): table[s][d] = (cos,sin) of
// s * 10000^(-d/32) -- 65K sincos once, replacing 6.3M in qkv's epilogue (RoPE trap).
__global__ __launch_bounds__(256) void cvt_all(const float* __restrict__ x,
                                               const float* __restrict__ Wq,
                                               const float* __restrict__ Wk,
                                               const float* __restrict__ Wv,
                                               const float* __restrict__ Wo,
                                               u16* __restrict__ xbf,
                                               u16* __restrict__ wbf,
                                               u16* __restrict__ wobf,
                                               float2* __restrict__ ropet) {
  int blk = blockIdx.x;                // 0..8447
  if (blk >= 8192) {
    const int idx = (blk - 8192) * 256 + threadIdx.x;   // 0..65535
    const int s = idx >> 5, d = idx & 31;
    const float invf = __expf((float)d * -0.2878231366f);  // 10000^(-d/32)
    float sv, cv;
    __sincosf((float)s * invf, &sv, &cv);
    ropet[idx] = make_float2(cv, sv);
    return;
  }
  const float* src;
  u16* dst;
  int i;
  if (blk < 4096) {
    src = x; dst = xbf; i = blk * 256 + threadIdx.x;
  } else {
    int wb = blk - 4096;               // 0..4095
    int sel = wb >> 10;
    src = (sel == 0) ? Wq : (sel == 1) ? Wk : (sel == 2) ? Wv : Wo;
    dst = (sel < 3) ? (wbf + (size_t)sel * 1048576) : wobf;
    i = (wb & 1023) * 256 + threadIdx.x;
  }
  float4 v = reinterpret_cast<const float4*>(src)[i];
  u16x4 o;
  o.x = f2bf(v.x); o.y = f2bf(v.y); o.z = f2bf(v.z); o.w = f2bf(v.w);
  reinterpret_cast<u16x4*>(dst)[i] = o;
}

// ---------------- templated GEMM, BK=32, double-buffered, XCD-chunked swizzle ----------------
__device__ __forceinline__ void store_out(float* p, float v) { *p = v; }
__device__ __forceinline__ void store_out(u16* p, float v) { *p = f2bf(v); }

template <typename OutT, int WM, int WN>
__global__ __launch_bounds__(256) void gemm_bt(const u16* __restrict__ A,
                                               const u16* __restrict__ Bw,
                                               OutT* __restrict__ C, int N, int K) {
  __shared__ u16 As[2][WM * 1024];
  __shared__ u16 Bs[2][WN * 1024];
  const int tid = threadIdx.x;
  const int lane = tid & 63;
  const int wave = tid >> 6;
  const int wm = wave >> 1, wn = wave & 1;
  const int lh = lane & 15, quad = lane >> 4;
  const int q8 = quad * 8;
  // XCD-chunked swizzle (T1): each XCD gets a compact W x (H/8) rectangle.
  int vbx = blockIdx.x, vby = blockIdx.y;
  if ((gridDim.y & 7) == 0) {
    const int W = gridDim.x;
    const int lin = blockIdx.y * W + blockIdx.x;   // hw x-fastest order
    const int xcd = lin & 7, slot = lin >> 3;
    vbx = slot % W;
    vby = xcd * (gridDim.y >> 3) + slot / W;
  }
  const int m0 = vby * (WM * 32), n0 = vbx * (WN * 32);
  constexpr int NCH = 2 * (WM + WN);
  constexpr int PER = NCH / 4;

  auto stage = [&](int buf, int kt) {
    const int kb = kt * 32;
#pragma unroll
    for (int i = 0; i < PER; ++i) {
      const int c = wave * PER + i;
      if (c < 2 * WM) {
        gload_lds16(A + (size_t)(m0 + c * 16 + lh) * K + kb + q8,
                    &As[buf][c * 512 + lane * 8]);
      } else {
        const int rb = c - 2 * WM;
        gload_lds16(Bw + (size_t)(n0 + rb * 16 + lh) * K + kb + q8,
                    &Bs[buf][rb * 512 + lane * 8]);
      }
    }
  };

  f32x4 acc[WM][WN];
#pragma unroll
  for (int i = 0; i < WM; ++i)
#pragma unroll
    for (int j = 0; j < WN; ++j) { acc[i][j][0] = 0.f; acc[i][j][1] = 0.f; acc[i][j][2] = 0.f; acc[i][j][3] = 0.f; }

  const int nkt = K >> 5;
  stage(0, 0);
  __syncthreads();  // drain DMA for tile 0
  for (int kt = 0; kt < nkt; ++kt) {
    const int p = kt & 1;
    if (kt < nkt - 1) stage(1 - p, kt + 1);  // prefetch; drained at the end barrier
    s16x8 af[WM], bf4[WN];
#pragma unroll
    for (int mb = 0; mb < WM; ++mb)
      af[mb] = *reinterpret_cast<const s16x8*>(&As[p][(wm * WM + mb) * 512 + lane * 8]);
#pragma unroll
    for (int nb = 0; nb < WN; ++nb)
      bf4[nb] = *reinterpret_cast<const s16x8*>(&Bs[p][(wn * WN + nb) * 512 + lane * 8]);
#pragma unroll
    for (int mb = 0; mb < WM; ++mb)
#pragma unroll
      for (int nb = 0; nb < WN; ++nb)
        acc[mb][nb] = __builtin_amdgcn_mfma_f32_16x16x32_bf16(af[mb], bf4[nb], acc[mb][nb], 0, 0, 0);
    __syncthreads();
  }
#pragma unroll
  for (int mb = 0; mb < WM; ++mb)
#pragma unroll
    for (int nb = 0; nb < WN; ++nb) {
      const int col = n0 + wn * (WN * 16) + nb * 16 + lh;
#pragma unroll
      for (int r = 0; r < 4; ++r) {
        const int row = m0 + wm * (WM * 16) + mb * 16 + quad * 4 + r;
        store_out(&C[(size_t)row * N + col], acc[mb][nb][r]);
      }
    }
}

// ---------------- QKV GEMM (BK=32, dbuf) + fused RoPE (table) + V-transpose, XCD swizzle ----------------
__global__ __launch_bounds__(256) void qkv_gemm(const u16* __restrict__ A,
                                                const u16* __restrict__ Bw,
                                                const float2* __restrict__ ropet,
                                                u16* __restrict__ Vt,
                                                u16* __restrict__ Qs,
                                                u16* __restrict__ Kb,
                                                u16* __restrict__ K2b) {
  __shared__ u16 As[2][4096];
  __shared__ u16 Bs[2][4096];
  const int tid = threadIdx.x;
  const int lane = tid & 63;
  const int wave = tid >> 6;
  const int wm = wave >> 1, wn = wave & 1;
  const int lh = lane & 15, quad = lane >> 4;
  const int q8 = quad * 8;
  // XCD-chunked swizzle: 768 blocks = 8 XCDs x (24 bx x 4 by).
  const int lin = blockIdx.y * 24 + blockIdx.x;   // hw x-fastest order
  const int xcd = lin & 7, slot = lin >> 3;       // slot 0..95
  const int bx = slot % 24;
  const int vby = xcd * 4 + slot / 24;
  const int m0 = vby * 128, n0 = bx * 128;
  const int K = 1024;

  auto stage = [&](int buf, int kt) {
    const int kb = kt * 32;
#pragma unroll
    for (int i = 0; i < 4; ++i) {
      const int c = wave * 4 + i;  // 0..15: 0-7 A chunks, 8-15 B chunks
      if (c < 8) {
        gload_lds16(A + (size_t)(m0 + c * 16 + lh) * K + kb + q8,
                    &As[buf][c * 512 + lane * 8]);
      } else {
        const int rb = c - 8;
        gload_lds16(Bw + (size_t)(n0 + rb * 16 + lh) * K + kb + q8,
                    &Bs[buf][rb * 512 + lane * 8]);
      }
    }
  };

  f32x4 acc[4][4];
#pragma unroll
  for (int i = 0; i < 4; ++i)
#pragma unroll
    for (int j = 0; j < 4; ++j) { acc[i][j][0] = 0.f; acc[i][j][1] = 0.f; acc[i][j][2] = 0.f; acc[i][j][3] = 0.f; }

  stage(0, 0);
  __syncthreads();
  for (int kt = 0; kt < 32; ++kt) {
    const int p = kt & 1;
    if (kt < 31) stage(1 - p, kt + 1);
    s16x8 af[4], bf4[4];
#pragma unroll
    for (int mb = 0; mb < 4; ++mb)
      af[mb] = *reinterpret_cast<const s16x8*>(&As[p][(wm * 4 + mb) * 512 + lane * 8]);
#pragma unroll
    for (int nb = 0; nb < 4; ++nb)
      bf4[nb] = *reinterpret_cast<const s16x8*>(&Bs[p][(wn * 4 + nb) * 512 + lane * 8]);
#pragma unroll
    for (int mb = 0; mb < 4; ++mb)
#pragma unroll
      for (int nb = 0; nb < 4; ++nb)
        acc[mb][nb] = __builtin_amdgcn_mfma_f32_16x16x32_bf16(af[mb], bf4[nb], acc[mb][nb], 0, 0, 0);
    __syncthreads();
  }

  if (bx < 16) {
    const bool isQ = (bx < 8);
#pragma unroll
    for (int nb = 0; nb < 2; ++nb) {
      const int d = nb * 16 + lh;                       // 0..31 (first half of head)
      const int col = n0 + wn * 64 + nb * 16 + lh;
      const int ch = col & 1023;                        // col within Q or K block
      const int h = ch >> 6;
#pragma unroll
      for (int mb = 0; mb < 4; ++mb)
#pragma unroll
        for (int r = 0; r < 4; ++r) {
          const int row = m0 + wm * 64 + mb * 16 + quad * 4 + r;
          const int s = row & 2047, b = row >> 11;
          const float2 cs = ropet[(s << 5) + d];        // (cos, sin) -- L2-hit 8B load
          const float v1 = acc[mb][nb][r], v2 = acc[mb][nb + 2][r];
          const float e0 = v1 * cs.x - v2 * cs.y;
          const float e1 = v2 * cs.x + v1 * cs.y;
          const size_t ofs = (size_t)((b * 16 + h) * 2048 + s) * 64 + d;
          if (isQ) {
            Qs[ofs]      = f2bf(e0 * 0.125f);
            Qs[ofs + 32] = f2bf(e1 * 0.125f);
          } else {
            Kb[ofs]       = f2bf(e0);
            Kb[ofs + 32]  = f2bf(e1);
            K2b[ofs]      = f2bf(e0 * e0);
            K2b[ofs + 32] = f2bf(e1 * e1);
          }
        }
    }
  } else {
    // V: direct transposed store. col -> (h, d); rows r are 4 consecutive s.
#pragma unroll
    for (int mb = 0; mb < 4; ++mb)
#pragma unroll
      for (int nb = 0; nb < 4; ++nb) {
        const int col = n0 + wn * 64 + nb * 16 + lh;
        const int ch = col & 1023;
        const int h = ch >> 6, d = ch & 63;
        const int row0 = m0 + wm * 64 + mb * 16 + quad * 4;
        const int s0 = row0 & 2047, b = row0 >> 11;
        u16x4 o;
#pragma unroll
        for (int r = 0; r < 4; ++r) o[r] = f2bf(acc[mb][nb][r]);
        *reinterpret_cast<u16x4*>(Vt + (size_t)((b * 16 + h) * 64 + d) * 2048 + s0) = o;
      }
  }
}

// ---------------- flash-style causal amplified attention, KVBLK=32, PV pipelined ----------------
// ROUND-6 VERSION VERBATIM (measured best: 73.8-75.2 us). Staged K/K2 DMA dbuf +
// cross-tile PV pipeline through parity-doubled Pbuf. Swapped-QK register-P variants
// (r8: 114, r9: 108) measured slower despite 0 bank conflicts -- do not revisit.
__global__ __launch_bounds__(256, 2) void attn_kernel(const u16* __restrict__ Qs,
                                                      const u16* __restrict__ Kb,
                                                      const u16* __restrict__ K2b,
                                                      const u16* __restrict__ Vt,
                                                      const float* __restrict__ gate,
                                                      u16* __restrict__ attn,
                                                      float* __restrict__ Opart,
                                                      float* __restrict__ Lpart,
                                                      float* __restrict__ Opart2,
                                                      float* __restrict__ Lpart2) {
  const int lin = blockIdx.y * 44 + blockIdx.x;
  const int xcd = lin & 7;
  const int slot = lin >> 3;          // 0..175
  const int bh = xcd * 4 + (slot / 44);
  const int bxv = slot % 44;

  int qi, kt0, kt1, chunk, which;
  bool split;
  if (bxv < 32) {
    qi = 15 - (bxv >> 2); chunk = bxv & 3; split = true; which = 0;
    const int T = 4 * qi + 4;                     // total key tiles (32-wide)
    kt0 = (chunk * T) >> 2;
    kt1 = (((chunk + 1) * T) >> 2) - 1;
  } else if (bxv < 40) {
    const int t = bxv - 32;
    qi = 7 - (t >> 1); chunk = t & 1; split = true; which = 1;
    const int nk = 2 * qi + 2; kt0 = chunk * nk; kt1 = kt0 + nk - 1;
  } else {
    qi = 43 - bxv; split = false; which = 0; chunk = 0; kt0 = 0; kt1 = 4 * qi + 3;
  }
  const int tid = threadIdx.x, lane = tid & 63, wave = tid >> 6;
  const int lh = lane & 15, quad = lane >> 4;
  const int b = bh >> 4, h = bh & 15;
  __shared__ u16 stageS[2][4096];      // [K chunks: 0..2047 | K2 chunks: 2048..4095]
  __shared__ u16 Pbuf[4][2][2][640];   // [wave][parity][mb]: 16 rows x 40
  const int base = qi * 128 + wave * 32;   // wave's first Q row
  const int q8 = quad * 8;

  auto do_stage = [&](int buf, int kt) {
#pragma unroll
    for (int i = 0; i < 2; ++i) {
      const int c = wave * 2 + i;   // 0..7; t2=c>>2 (0=K,1=K2), f=c&3 = kk*2+nb
      const int t2 = c >> 2, f = c & 3, kk = f >> 1, nb = f & 1;
      const u16* src = (t2 ? K2b : Kb) +
          (size_t)(bh * 2048 + kt * 32 + nb * 16 + lh) * 64 + kk * 32 + q8;
      gload_lds16(src, &stageS[buf][t2 * 2048 + f * 512 + lane * 8]);
    }
  };

  // Q fragments (A-layout): m = lh, k = kk*32 + quad*8 + j ; q/8 pre-scaled in memory.
  s16x8 qf[2][2], q2f[2][2];
#pragma unroll
  for (int mb = 0; mb < 2; ++mb) {
    const size_t qoff = (size_t)(bh * 2048 + base + mb * 16 + lh) * 64 + q8;
#pragma unroll
    for (int kk = 0; kk < 2; ++kk) {
      qf[mb][kk] = *reinterpret_cast<const s16x8*>(Qs + qoff + kk * 32);
#pragma unroll
      for (int j = 0; j < 8; ++j) {
        float f = bf2f((u16)qf[mb][kk][j]);
        q2f[mb][kk][j] = (short)f2bf(f * f * 0.8f);
      }
    }
  }

  const u16* Vbase = Vt + (size_t)bh * 131072;

  f32x4 oacc[2][4];
  float lsum[2][4];
#pragma unroll
  for (int mb = 0; mb < 2; ++mb)
#pragma unroll
    for (int nb = 0; nb < 4; ++nb) { oacc[mb][nb][0] = 0.f; oacc[mb][nb][1] = 0.f; oacc[mb][nb][2] = 0.f; oacc[mb][nb][3] = 0.f; }
#pragma unroll
  for (int mb = 0; mb < 2; ++mb)
#pragma unroll
    for (int r = 0; r < 4; ++r) lsum[mb][r] = 0.f;

  do_stage(0, kt0);
  __syncthreads();  // drain DMA for first tile

  s16x8 vfp[4];     // V frags of the PENDING tile (PV deferred one iteration)
  int pvalid = 0;
  int pendp = 0;    // Pbuf parity of the pending tile

  const int wmaxrow = base + 31;
  for (int kt = kt0; kt <= kt1; ++kt) {
    const int p = (kt - kt0) & 1;
    if (kt < kt1) do_stage(1 - p, kt + 1);  // async prefetch, drained at end barrier

    if (kt * 32 <= wmaxrow) {  // wave-uniform skip of fully-masked tiles
      const u16* Ks = stageS[p];
      f32x4 sacc[2][2];
#pragma unroll
      for (int mb = 0; mb < 2; ++mb)
#pragma unroll
        for (int nb = 0; nb < 2; ++nb) { sacc[mb][nb][0] = -8.f; sacc[mb][nb][1] = -8.f; sacc[mb][nb][2] = -8.f; sacc[mb][nb][3] = -8.f; }
      __builtin_amdgcn_s_setprio(1);
#pragma unroll
      for (int nb = 0; nb < 2; ++nb)
#pragma unroll
        for (int kk = 0; kk < 2; ++kk) {
          s16x8 kf  = *reinterpret_cast<const s16x8*>(&Ks[(kk * 2 + nb) * 512 + lane * 8]);
          s16x8 k2f = *reinterpret_cast<const s16x8*>(&Ks[2048 + (kk * 2 + nb) * 512 + lane * 8]);
#pragma unroll
          for (int mb = 0; mb < 2; ++mb) {
            sacc[mb][nb] = __builtin_amdgcn_mfma_f32_16x16x32_bf16(qf[mb][kk],  kf,  sacc[mb][nb], 0, 0, 0);
            sacc[mb][nb] = __builtin_amdgcn_mfma_f32_16x16x32_bf16(q2f[mb][kk], k2f, sacc[mb][nb], 0, 0, 0);
          }
        }
      // pending PV (previous tile): P-read latency + MFMAs overlap QK above / exp below
      if (pvalid) {
#pragma unroll
        for (int mb = 0; mb < 2; ++mb) {
          s16x8 pf = *reinterpret_cast<const s16x8*>(&Pbuf[wave][pendp][mb][lh * 40 + q8]);
#pragma unroll
          for (int nb = 0; nb < 4; ++nb)
            oacc[mb][nb] = __builtin_amdgcn_mfma_f32_16x16x32_bf16(pf, vfp[nb], oacc[mb][nb], 0, 0, 0);
        }
      }
      __builtin_amdgcn_s_setprio(0);

      if (kt * 32 + 31 > base) {  // tiles overlapping the diagonal: elementwise mask
#pragma unroll
        for (int mb = 0; mb < 2; ++mb)
#pragma unroll
          for (int nb = 0; nb < 2; ++nb) {
            const int colg = kt * 32 + nb * 16 + lh;
#pragma unroll
            for (int r = 0; r < 4; ++r) {
              const int rowg = base + mb * 16 + quad * 4 + r;
              if (colg > rowg) sacc[mb][nb][r] = -1e9f;
            }
          }
      }
      // p = exp(s - 8): write Pbuf parity p; PV happens next iteration (or tail)
#pragma unroll
      for (int mb = 0; mb < 2; ++mb)
#pragma unroll
        for (int nb = 0; nb < 2; ++nb)
#pragma unroll
          for (int r = 0; r < 4; ++r) {
            float pv = __expf(sacc[mb][nb][r]);
            lsum[mb][r] += pv;
            Pbuf[wave][p][mb][(quad * 4 + r) * 40 + nb * 16 + lh] = f2bf(pv);
          }
      // V fragments for THIS tile, consumed next iteration (drain is free at barrier)
#pragma unroll
      for (int nb = 0; nb < 4; ++nb)
        vfp[nb] = *reinterpret_cast<const s16x8*>(
            Vbase + (size_t)(nb * 16 + lh) * 2048 + kt * 32 + q8);
      pvalid = 1; pendp = p;
    }
    __syncthreads();  // all waves done with stageS[p]; prefetch for kt+1 drained
  }
  // tail: PV of the last computed tile
  if (pvalid) {
#pragma unroll
    for (int mb = 0; mb < 2; ++mb) {
      s16x8 pf = *reinterpret_cast<const s16x8*>(&Pbuf[wave][pendp][mb][lh * 40 + q8]);
#pragma unroll
      for (int nb = 0; nb < 4; ++nb)
        oacc[mb][nb] = __builtin_amdgcn_mfma_f32_16x16x32_bf16(pf, vfp[nb], oacc[mb][nb], 0, 0, 0);
    }
  }
  // reduce row sums across the 16 lanes holding each row
#pragma unroll
  for (int mb = 0; mb < 2; ++mb)
#pragma unroll
    for (int r = 0; r < 4; ++r) {
      float rs = lsum[mb][r];
#pragma unroll
      for (int off = 1; off < 16; off <<= 1) rs += __shfl_xor(rs, off);
      lsum[mb][r] = rs;
    }
  if (split) {
    // unnormalized partials to ws (fp32)
#pragma unroll
    for (int mb = 0; mb < 2; ++mb)
#pragma unroll
      for (int r = 0; r < 4; ++r) {
        const int rowg = base + mb * 16 + quad * 4 + r;
        if (which == 0) {
          const size_t orow = (size_t)chunk * 32768 + bh * 1024 + (rowg - 1024);
          if (lh == 0) Lpart[orow] = lsum[mb][r];
#pragma unroll
          for (int nb = 0; nb < 4; ++nb)
            Opart[orow * 64 + nb * 16 + lh] = oacc[mb][nb][r];
        } else {
          const size_t orow = (size_t)chunk * 16384 + bh * 512 + (rowg - 512);
          if (lh == 0) Lpart2[orow] = lsum[mb][r];
#pragma unroll
          for (int nb = 0; nb < 4; ++nb)
            Opart2[orow * 64 + nb * 16 + lh] = oacc[mb][nb][r];
        }
      }
  } else {
    // finalize: o/l, epilogue o + 0.05*o^2*g[d] (out2==out1 identity)
#pragma unroll
    for (int mb = 0; mb < 2; ++mb)
#pragma unroll
      for (int r = 0; r < 4; ++r) {
        const float invl = 1.0f / lsum[mb][r];
        const int rows = base + mb * 16 + quad * 4 + r;
#pragma unroll
        for (int nb = 0; nb < 4; ++nb) {
          float o = oacc[mb][nb][r] * invl;
          float val = o + 0.05f * o * o * gate[nb * 16 + lh];
          attn[(size_t)(b * 2048 + rows) * 1024 + h * 64 + nb * 16 + lh] = f2bf(val);
        }
      }
  }
}

// ---------------- combine split-K partials (rows 512..2047) ----------------
__global__ __launch_bounds__(256) void combine_kernel(const float* __restrict__ Opart,
                                                      const float* __restrict__ Lpart,
                                                      const float* __restrict__ Opart2,
                                                      const float* __restrict__ Lpart2,
                                                      const float* __restrict__ gate,
                                                      u16* __restrict__ attn) {
  int idx = blockIdx.x * 256 + threadIdx.x;   // 0 .. 3145727
  int d = idx & 63;
  int r_all = idx >> 6;
  float o, l;
  int bh, s;
  if (r_all < 32768) {            // rows s >= 1024 (qi >= 8): 4 chunks
    o = Opart[idx] + Opart[idx + 2097152] + Opart[idx + 4194304] + Opart[idx + 6291456];
    l = Lpart[r_all] + Lpart[r_all + 32768] + Lpart[r_all + 65536] + Lpart[r_all + 98304];
    bh = r_all >> 10; s = 1024 + (r_all & 1023);
  } else {                        // rows 512..1023 (qi 4..7): 2 chunks
    const int r2 = r_all - 32768;
    const int i2 = idx - 2097152;
    o = Opart2[i2] + Opart2[i2 + 1048576];
    l = Lpart2[r2] + Lpart2[r2 + 16384];
    bh = r2 >> 9; s = 512 + (r2 & 511);
  }
  o /= l;
  float val = o + 0.05f * o * o * gate[d];
  int b = bh >> 4, h = bh & 15;
  attn[(size_t)(b * 2048 + s) * 1024 + h * 64 + d] = f2bf(val);
}

extern "C" void kernel_launch(void* const* d_in, const int* in_sizes, int n_in,
                              void* d_out, int out_size, void* d_ws, size_t ws_size,
                              hipStream_t stream) {
  (void)in_sizes; (void)n_in; (void)out_size; (void)ws_size;
  const float* x    = (const float*)d_in[0];
  const float* Wq   = (const float*)d_in[1];
  const float* Wk   = (const float*)d_in[2];
  const float* Wv   = (const float*)d_in[3];
  const float* Wo   = (const float*)d_in[4];
  const float* gate = (const float*)d_in[5];

  u16* ws    = (u16*)d_ws;
  u16* xbf   = ws;                    // 4096x1024 bf16 (qkv A input; attn out aliases later)
  u16* wbf   = xbf + 4194304;         // 3072x1024 (Wq|Wk|Wv rows)
  u16* wobf  = wbf + 3145728;         // 1024x1024
  u16* Qsb   = wobf + 1048576;        // (B,H,S,64) q/8
  u16* Kbb   = Qsb + 4194304;         // (B,H,S,64)
  u16* K2bb  = Kbb + 4194304;         // (B,H,S,64)
  u16* Vtb   = K2bb + 4194304;        // (B,H,64,S)  (written directly by qkv epilogue)
  float* Opart  = (float*)(Vtb + 4194304); // 4 x 32 x 1024 x 64 fp32 (33.6 MB)
  float* Lpart  = Opart + 8388608;         // 4 x 32 x 1024 fp32
  float* Opart2 = Lpart + 131072;          // 2 x 32 x 512 x 64 fp32 (8.4 MB)
  float* Lpart2 = Opart2 + 2097152;        // 2 x 32 x 512 fp32
  u16* attnb = xbf;                   // alias: attn out (xbf dead after qkv_gemm)
  // RoPE table aliases the head of Opart (512 KB of 33.6 MB): written by cvt_all,
  // read by qkv_gemm, clobbered later by attn_kernel -- stream order makes it safe.
  float2* ropet = (float2*)Opart;

  cvt_all<<<8448, 256, 0, stream>>>(x, Wq, Wk, Wv, Wo, xbf, wbf, wobf, ropet);
  qkv_gemm<<<dim3(24, 32), 256, 0, stream>>>(xbf, wbf, ropet, Vtb, Qsb, Kbb, K2bb);
  attn_kernel<<<dim3(44, 32), 256, 0, stream>>>(Qsb, Kbb, K2bb, Vtb, gate, attnb,
                                                Opart, Lpart, Opart2, Lpart2);
  combine_kernel<<<12288, 256, 0, stream>>>(Opart, Lpart, Opart2, Lpart2, gate, attnb);
  gemm_bt<float, 4, 2><<<dim3(16, 32), 256, 0, stream>>>(attnb, wobf, (float*)d_out, 1024, 1024);
}

// Round 11
// 238.517 us; speedup vs baseline: 1.1699x; 1.0294x over previous
//
#include <hip/hip_runtime.h>

typedef unsigned short u16;
typedef __attribute__((ext_vector_type(4))) unsigned short u16x4;
typedef __attribute__((ext_vector_type(8))) unsigned short u16x8;
typedef __attribute__((ext_vector_type(8))) short s16x8;
typedef __attribute__((ext_vector_type(4))) float f32x4;

__device__ __forceinline__ u16 f2bf(float f) {
  unsigned int u = __float_as_uint(f);
  u += 0x7FFFu + ((u >> 16) & 1u);   // RNE
  return (u16)(u >> 16);
}
__device__ __forceinline__ float bf2f(u16 h) {
  return __uint_as_float(((unsigned int)h) << 16);
}

// async global->LDS, 16B per lane; base = lane0's lds ptr, lane i writes base+i*16B.
__device__ __forceinline__ void gload_lds16(const u16* g, u16* l) {
  __builtin_amdgcn_global_load_lds(
      (const __attribute__((address_space(1))) unsigned int*)(g),
      (__attribute__((address_space(3))) unsigned int*)(l), 16, 0, 0);
}

// ---------------- fused fp32 -> bf16 convert: x + all four weights ----------------
__global__ __launch_bounds__(256) void cvt_all(const float* __restrict__ x,
                                               const float* __restrict__ Wq,
                                               const float* __restrict__ Wk,
                                               const float* __restrict__ Wv,
                                               const float* __restrict__ Wo,
                                               u16* __restrict__ xbf,
                                               u16* __restrict__ wbf,
                                               u16* __restrict__ wobf) {
  int blk = blockIdx.x;                // 0..8191
  const float* src;
  u16* dst;
  int i;
  if (blk < 4096) {
    src = x; dst = xbf; i = blk * 256 + threadIdx.x;
  } else {
    int wb = blk - 4096;               // 0..4095
    int sel = wb >> 10;
    src = (sel == 0) ? Wq : (sel == 1) ? Wk : (sel == 2) ? Wv : Wo;
    dst = (sel < 3) ? (wbf + (size_t)sel * 1048576) : wobf;
    i = (wb & 1023) * 256 + threadIdx.x;
  }
  float4 v = reinterpret_cast<const float4*>(src)[i];
  u16x4 o;
  o.x = f2bf(v.x); o.y = f2bf(v.y); o.z = f2bf(v.z); o.w = f2bf(v.w);
  reinterpret_cast<u16x4*>(dst)[i] = o;
}

// ---------------- templated GEMM, BK=32, double-buffered, XCD-chunked swizzle ----------------
__device__ __forceinline__ void store_out(float* p, float v) { *p = v; }
__device__ __forceinline__ void store_out(u16* p, float v) { *p = f2bf(v); }

template <typename OutT, int WM, int WN>
__global__ __launch_bounds__(256) void gemm_bt(const u16* __restrict__ A,
                                               const u16* __restrict__ Bw,
                                               OutT* __restrict__ C, int N, int K) {
  __shared__ u16 As[2][WM * 1024];
  __shared__ u16 Bs[2][WN * 1024];
  const int tid = threadIdx.x;
  const int lane = tid & 63;
  const int wave = tid >> 6;
  const int wm = wave >> 1, wn = wave & 1;
  const int lh = lane & 15, quad = lane >> 4;
  const int q8 = quad * 8;
  // XCD-chunked swizzle (T1): each XCD gets a compact W x (H/8) rectangle.
  int vbx = blockIdx.x, vby = blockIdx.y;
  if ((gridDim.y & 7) == 0) {
    const int W = gridDim.x;
    const int lin = blockIdx.y * W + blockIdx.x;   // hw x-fastest order
    const int xcd = lin & 7, slot = lin >> 3;
    vbx = slot % W;
    vby = xcd * (gridDim.y >> 3) + slot / W;
  }
  const int m0 = vby * (WM * 32), n0 = vbx * (WN * 32);
  constexpr int NCH = 2 * (WM + WN);
  constexpr int PER = NCH / 4;

  auto stage = [&](int buf, int kt) {
    const int kb = kt * 32;
#pragma unroll
    for (int i = 0; i < PER; ++i) {
      const int c = wave * PER + i;
      if (c < 2 * WM) {
        gload_lds16(A + (size_t)(m0 + c * 16 + lh) * K + kb + q8,
                    &As[buf][c * 512 + lane * 8]);
      } else {
        const int rb = c - 2 * WM;
        gload_lds16(Bw + (size_t)(n0 + rb * 16 + lh) * K + kb + q8,
                    &Bs[buf][rb * 512 + lane * 8]);
      }
    }
  };

  f32x4 acc[WM][WN];
#pragma unroll
  for (int i = 0; i < WM; ++i)
#pragma unroll
    for (int j = 0; j < WN; ++j) { acc[i][j][0] = 0.f; acc[i][j][1] = 0.f; acc[i][j][2] = 0.f; acc[i][j][3] = 0.f; }

  const int nkt = K >> 5;
  stage(0, 0);
  __syncthreads();  // drain DMA for tile 0
  for (int kt = 0; kt < nkt; ++kt) {
    const int p = kt & 1;
    if (kt < nkt - 1) stage(1 - p, kt + 1);  // prefetch; drained at the end barrier
    s16x8 af[WM], bf4[WN];
#pragma unroll
    for (int mb = 0; mb < WM; ++mb)
      af[mb] = *reinterpret_cast<const s16x8*>(&As[p][(wm * WM + mb) * 512 + lane * 8]);
#pragma unroll
    for (int nb = 0; nb < WN; ++nb)
      bf4[nb] = *reinterpret_cast<const s16x8*>(&Bs[p][(wn * WN + nb) * 512 + lane * 8]);
#pragma unroll
    for (int mb = 0; mb < WM; ++mb)
#pragma unroll
      for (int nb = 0; nb < WN; ++nb)
        acc[mb][nb] = __builtin_amdgcn_mfma_f32_16x16x32_bf16(af[mb], bf4[nb], acc[mb][nb], 0, 0, 0);
    __syncthreads();
  }
#pragma unroll
  for (int mb = 0; mb < WM; ++mb)
#pragma unroll
    for (int nb = 0; nb < WN; ++nb) {
      const int col = n0 + wn * (WN * 16) + nb * 16 + lh;
#pragma unroll
      for (int r = 0; r < 4; ++r) {
        const int row = m0 + wm * (WM * 16) + mb * 16 + quad * 4 + r;
        store_out(&C[(size_t)row * N + col], acc[mb][nb][r]);
      }
    }
}

// ---------------- QKV GEMM (BK=32, dbuf) + fused RoPE + LDS-transposed V store ----------------
// smem layout: mainloop A buf0/buf1 at [0],[4096]; B buf0/buf1 at [8192],[12288].
// After the final barrier the V-branch reuses smem as a [128 col][136 stride] u16
// transpose tile (34 KB): acc -> LDS (conflict-free 8B writes) -> fully-coalesced
// 16B global stores (each (h,d) row's 256B span written by 16 consecutive lanes).
// Old V path was 16x 8B stores at 4KB stride per thread (64-line scatter per instr).
__global__ __launch_bounds__(256) void qkv_gemm(const u16* __restrict__ A,
                                                const u16* __restrict__ Bw,
                                                u16* __restrict__ Vt,
                                                u16* __restrict__ Qs,
                                                u16* __restrict__ Kb,
                                                u16* __restrict__ K2b) {
  __shared__ u16 smem[17408];   // 34 KB
  const int tid = threadIdx.x;
  const int lane = tid & 63;
  const int wave = tid >> 6;
  const int wm = wave >> 1, wn = wave & 1;
  const int lh = lane & 15, quad = lane >> 4;
  const int q8 = quad * 8;
  // XCD-chunked swizzle: 768 blocks = 8 XCDs x (24 bx x 4 by).
  const int lin = blockIdx.y * 24 + blockIdx.x;   // hw x-fastest order
  const int xcd = lin & 7, slot = lin >> 3;       // slot 0..95
  const int bx = slot % 24;
  const int vby = xcd * 4 + slot / 24;
  const int m0 = vby * 128, n0 = bx * 128;
  const int K = 1024;

  auto stage = [&](int buf, int kt) {
    const int kb = kt * 32;
#pragma unroll
    for (int i = 0; i < 4; ++i) {
      const int c = wave * 4 + i;  // 0..15: 0-7 A chunks, 8-15 B chunks
      if (c < 8) {
        gload_lds16(A + (size_t)(m0 + c * 16 + lh) * K + kb + q8,
                    smem + buf * 4096 + c * 512 + lane * 8);
      } else {
        const int rb = c - 8;
        gload_lds16(Bw + (size_t)(n0 + rb * 16 + lh) * K + kb + q8,
                    smem + 8192 + buf * 4096 + rb * 512 + lane * 8);
      }
    }
  };

  f32x4 acc[4][4];
#pragma unroll
  for (int i = 0; i < 4; ++i)
#pragma unroll
    for (int j = 0; j < 4; ++j) { acc[i][j][0] = 0.f; acc[i][j][1] = 0.f; acc[i][j][2] = 0.f; acc[i][j][3] = 0.f; }

  stage(0, 0);
  __syncthreads();
  for (int kt = 0; kt < 32; ++kt) {
    const int p = kt & 1;
    if (kt < 31) stage(1 - p, kt + 1);
    s16x8 af[4], bf4[4];
#pragma unroll
    for (int mb = 0; mb < 4; ++mb)
      af[mb] = *reinterpret_cast<const s16x8*>(&smem[p * 4096 + (wm * 4 + mb) * 512 + lane * 8]);
#pragma unroll
    for (int nb = 0; nb < 4; ++nb)
      bf4[nb] = *reinterpret_cast<const s16x8*>(&smem[8192 + p * 4096 + (wn * 4 + nb) * 512 + lane * 8]);
#pragma unroll
    for (int mb = 0; mb < 4; ++mb)
#pragma unroll
      for (int nb = 0; nb < 4; ++nb)
        acc[mb][nb] = __builtin_amdgcn_mfma_f32_16x16x32_bf16(af[mb], bf4[nb], acc[mb][nb], 0, 0, 0);
    __syncthreads();
  }

  if (bx < 16) {
    const bool isQ = (bx < 8);
#pragma unroll
    for (int nb = 0; nb < 2; ++nb) {
      const int d = nb * 16 + lh;                       // 0..31 (first half of head)
      const float invf = __expf((float)d * -0.2878231366f);  // 10000^(-d/32)
      const int col = n0 + wn * 64 + nb * 16 + lh;
      const int ch = col & 1023;                        // col within Q or K block
      const int h = ch >> 6;
#pragma unroll
      for (int mb = 0; mb < 4; ++mb)
#pragma unroll
        for (int r = 0; r < 4; ++r) {
          const int row = m0 + wm * 64 + mb * 16 + quad * 4 + r;
          const int s = row & 2047, b = row >> 11;
          float ang = (float)s * invf;
          float sv, cv;
          __sincosf(ang, &sv, &cv);
          const float v1 = acc[mb][nb][r], v2 = acc[mb][nb + 2][r];
          const float e0 = v1 * cv - v2 * sv;
          const float e1 = v2 * cv + v1 * sv;
          const size_t ofs = (size_t)((b * 16 + h) * 2048 + s) * 64 + d;
          if (isQ) {
            Qs[ofs]      = f2bf(e0 * 0.125f);
            Qs[ofs + 32] = f2bf(e1 * 0.125f);
          } else {
            Kb[ofs]       = f2bf(e0);
            Kb[ofs + 32]  = f2bf(e1);
            K2b[ofs]      = f2bf(e0 * e0);
            K2b[ofs + 32] = f2bf(e1 * e1);
          }
        }
    }
  } else {
    // V: LDS transpose then coalesced store.
    constexpr int STR = 136;   // u16 stride: 272B = 17 x 16B (16B-aligned rows, bank-spread)
    // phase 1: acc -> smem[c_local][s_local]
#pragma unroll
    for (int mb = 0; mb < 4; ++mb)
#pragma unroll
      for (int nb = 0; nb < 4; ++nb) {
        const int c_local = wn * 64 + nb * 16 + lh;            // 0..127
        const int s_loc0 = wm * 64 + mb * 16 + quad * 4;       // 0..124 (mult of 4)
        u16x4 o;
#pragma unroll
        for (int r = 0; r < 4; ++r) o[r] = f2bf(acc[mb][nb][r]);
        *reinterpret_cast<u16x4*>(&smem[c_local * STR + s_loc0]) = o;
      }
    __syncthreads();
    // phase 2: 128 rows x 256B, 16B chunks; 2048 chunks over 256 threads = 8 iters.
    const int chbase = n0 & 1023;       // first col of block within V's 1024
    const int b = m0 >> 11;
    const int s0 = m0 & 2047;
#pragma unroll
    for (int it = 0; it < 8; ++it) {
      const int cid = it * 256 + tid;   // 0..2047
      const int cl = cid >> 4;          // col_local 0..127
      const int j  = cid & 15;          // 16B chunk within the 256B row
      const int ch = chbase + cl;
      const int h = ch >> 6, d = ch & 63;
      u16x8 v = *reinterpret_cast<const u16x8*>(&smem[cl * STR + j * 8]);
      *reinterpret_cast<u16x8*>(
          Vt + (size_t)((b * 16 + h) * 64 + d) * 2048 + s0 + j * 8) = v;
    }
  }
}

// ---------------- flash-style causal amplified attention, KVBLK=32, PV pipelined ----------------
// ROUND-6 VERSION VERBATIM (measured 71.6-75.2 us across sessions; best attn variant).
// Swapped-QK register-P variants (r8: 114, r9: 108) measured slower -- do not revisit.
__global__ __launch_bounds__(256, 2) void attn_kernel(const u16* __restrict__ Qs,
                                                      const u16* __restrict__ Kb,
                                                      const u16* __restrict__ K2b,
                                                      const u16* __restrict__ Vt,
                                                      const float* __restrict__ gate,
                                                      u16* __restrict__ attn,
                                                      float* __restrict__ Opart,
                                                      float* __restrict__ Lpart,
                                                      float* __restrict__ Opart2,
                                                      float* __restrict__ Lpart2) {
  const int lin = blockIdx.y * 44 + blockIdx.x;
  const int xcd = lin & 7;
  const int slot = lin >> 3;          // 0..175
  const int bh = xcd * 4 + (slot / 44);
  const int bxv = slot % 44;

  int qi, kt0, kt1, chunk, which;
  bool split;
  if (bxv < 32) {
    qi = 15 - (bxv >> 2); chunk = bxv & 3; split = true; which = 0;
    const int T = 4 * qi + 4;                     // total key tiles (32-wide)
    kt0 = (chunk * T) >> 2;
    kt1 = (((chunk + 1) * T) >> 2) - 1;
  } else if (bxv < 40) {
    const int t = bxv - 32;
    qi = 7 - (t >> 1); chunk = t & 1; split = true; which = 1;
    const int nk = 2 * qi + 2; kt0 = chunk * nk; kt1 = kt0 + nk - 1;
  } else {
    qi = 43 - bxv; split = false; which = 0; chunk = 0; kt0 = 0; kt1 = 4 * qi + 3;
  }
  const int tid = threadIdx.x, lane = tid & 63, wave = tid >> 6;
  const int lh = lane & 15, quad = lane >> 4;
  const int b = bh >> 4, h = bh & 15;
  __shared__ u16 stageS[2][4096];      // [K chunks: 0..2047 | K2 chunks: 2048..4095]
  __shared__ u16 Pbuf[4][2][2][640];   // [wave][parity][mb]: 16 rows x 40
  const int base = qi * 128 + wave * 32;   // wave's first Q row
  const int q8 = quad * 8;

  auto do_stage = [&](int buf, int kt) {
#pragma unroll
    for (int i = 0; i < 2; ++i) {
      const int c = wave * 2 + i;   // 0..7; t2=c>>2 (0=K,1=K2), f=c&3 = kk*2+nb
      const int t2 = c >> 2, f = c & 3, kk = f >> 1, nb = f & 1;
      const u16* src = (t2 ? K2b : Kb) +
          (size_t)(bh * 2048 + kt * 32 + nb * 16 + lh) * 64 + kk * 32 + q8;
      gload_lds16(src, &stageS[buf][t2 * 2048 + f * 512 + lane * 8]);
    }
  };

  // Q fragments (A-layout): m = lh, k = kk*32 + quad*8 + j ; q/8 pre-scaled in memory.
  s16x8 qf[2][2], q2f[2][2];
#pragma unroll
  for (int mb = 0; mb < 2; ++mb) {
    const size_t qoff = (size_t)(bh * 2048 + base + mb * 16 + lh) * 64 + q8;
#pragma unroll
    for (int kk = 0; kk < 2; ++kk) {
      qf[mb][kk] = *reinterpret_cast<const s16x8*>(Qs + qoff + kk * 32);
#pragma unroll
      for (int j = 0; j < 8; ++j) {
        float f = bf2f((u16)qf[mb][kk][j]);
        q2f[mb][kk][j] = (short)f2bf(f * f * 0.8f);
      }
    }
  }

  const u16* Vbase = Vt + (size_t)bh * 131072;

  f32x4 oacc[2][4];
  float lsum[2][4];
#pragma unroll
  for (int mb = 0; mb < 2; ++mb)
#pragma unroll
    for (int nb = 0; nb < 4; ++nb) { oacc[mb][nb][0] = 0.f; oacc[mb][nb][1] = 0.f; oacc[mb][nb][2] = 0.f; oacc[mb][nb][3] = 0.f; }
#pragma unroll
  for (int mb = 0; mb < 2; ++mb)
#pragma unroll
    for (int r = 0; r < 4; ++r) lsum[mb][r] = 0.f;

  do_stage(0, kt0);
  __syncthreads();  // drain DMA for first tile

  s16x8 vfp[4];     // V frags of the PENDING tile (PV deferred one iteration)
  int pvalid = 0;
  int pendp = 0;    // Pbuf parity of the pending tile

  const int wmaxrow = base + 31;
  for (int kt = kt0; kt <= kt1; ++kt) {
    const int p = (kt - kt0) & 1;
    if (kt < kt1) do_stage(1 - p, kt + 1);  // async prefetch, drained at end barrier

    if (kt * 32 <= wmaxrow) {  // wave-uniform skip of fully-masked tiles
      const u16* Ks = stageS[p];
      f32x4 sacc[2][2];
#pragma unroll
      for (int mb = 0; mb < 2; ++mb)
#pragma unroll
        for (int nb = 0; nb < 2; ++nb) { sacc[mb][nb][0] = -8.f; sacc[mb][nb][1] = -8.f; sacc[mb][nb][2] = -8.f; sacc[mb][nb][3] = -8.f; }
      __builtin_amdgcn_s_setprio(1);
#pragma unroll
      for (int nb = 0; nb < 2; ++nb)
#pragma unroll
        for (int kk = 0; kk < 2; ++kk) {
          s16x8 kf  = *reinterpret_cast<const s16x8*>(&Ks[(kk * 2 + nb) * 512 + lane * 8]);
          s16x8 k2f = *reinterpret_cast<const s16x8*>(&Ks[2048 + (kk * 2 + nb) * 512 + lane * 8]);
#pragma unroll
          for (int mb = 0; mb < 2; ++mb) {
            sacc[mb][nb] = __builtin_amdgcn_mfma_f32_16x16x32_bf16(qf[mb][kk],  kf,  sacc[mb][nb], 0, 0, 0);
            sacc[mb][nb] = __builtin_amdgcn_mfma_f32_16x16x32_bf16(q2f[mb][kk], k2f, sacc[mb][nb], 0, 0, 0);
          }
        }
      // pending PV (previous tile): P-read latency + MFMAs overlap QK above / exp below
      if (pvalid) {
#pragma unroll
        for (int mb = 0; mb < 2; ++mb) {
          s16x8 pf = *reinterpret_cast<const s16x8*>(&Pbuf[wave][pendp][mb][lh * 40 + q8]);
#pragma unroll
          for (int nb = 0; nb < 4; ++nb)
            oacc[mb][nb] = __builtin_amdgcn_mfma_f32_16x16x32_bf16(pf, vfp[nb], oacc[mb][nb], 0, 0, 0);
        }
      }
      __builtin_amdgcn_s_setprio(0);

      if (kt * 32 + 31 > base) {  // tiles overlapping the diagonal: elementwise mask
#pragma unroll
        for (int mb = 0; mb < 2; ++mb)
#pragma unroll
          for (int nb = 0; nb < 2; ++nb) {
            const int colg = kt * 32 + nb * 16 + lh;
#pragma unroll
            for (int r = 0; r < 4; ++r) {
              const int rowg = base + mb * 16 + quad * 4 + r;
              if (colg > rowg) sacc[mb][nb][r] = -1e9f;
            }
          }
      }
      // p = exp(s - 8): write Pbuf parity p; PV happens next iteration (or tail)
#pragma unroll
      for (int mb = 0; mb < 2; ++mb)
#pragma unroll
        for (int nb = 0; nb < 2; ++nb)
#pragma unroll
          for (int r = 0; r < 4; ++r) {
            float pv = __expf(sacc[mb][nb][r]);
            lsum[mb][r] += pv;
            Pbuf[wave][p][mb][(quad * 4 + r) * 40 + nb * 16 + lh] = f2bf(pv);
          }
      // V fragments for THIS tile, consumed next iteration (drain is free at barrier)
#pragma unroll
      for (int nb = 0; nb < 4; ++nb)
        vfp[nb] = *reinterpret_cast<const s16x8*>(
            Vbase + (size_t)(nb * 16 + lh) * 2048 + kt * 32 + q8);
      pvalid = 1; pendp = p;
    }
    __syncthreads();  // all waves done with stageS[p]; prefetch for kt+1 drained
  }
  // tail: PV of the last computed tile
  if (pvalid) {
#pragma unroll
    for (int mb = 0; mb < 2; ++mb) {
      s16x8 pf = *reinterpret_cast<const s16x8*>(&Pbuf[wave][pendp][mb][lh * 40 + q8]);
#pragma unroll
      for (int nb = 0; nb < 4; ++nb)
        oacc[mb][nb] = __builtin_amdgcn_mfma_f32_16x16x32_bf16(pf, vfp[nb], oacc[mb][nb], 0, 0, 0);
    }
  }
  // reduce row sums across the 16 lanes holding each row
#pragma unroll
  for (int mb = 0; mb < 2; ++mb)
#pragma unroll
    for (int r = 0; r < 4; ++r) {
      float rs = lsum[mb][r];
#pragma unroll
      for (int off = 1; off < 16; off <<= 1) rs += __shfl_xor(rs, off);
      lsum[mb][r] = rs;
    }
  if (split) {
    // unnormalized partials to ws (fp32)
#pragma unroll
    for (int mb = 0; mb < 2; ++mb)
#pragma unroll
      for (int r = 0; r < 4; ++r) {
        const int rowg = base + mb * 16 + quad * 4 + r;
        if (which == 0) {
          const size_t orow = (size_t)chunk * 32768 + bh * 1024 + (rowg - 1024);
          if (lh == 0) Lpart[orow] = lsum[mb][r];
#pragma unroll
          for (int nb = 0; nb < 4; ++nb)
            Opart[orow * 64 + nb * 16 + lh] = oacc[mb][nb][r];
        } else {
          const size_t orow = (size_t)chunk * 16384 + bh * 512 + (rowg - 512);
          if (lh == 0) Lpart2[orow] = lsum[mb][r];
#pragma unroll
          for (int nb = 0; nb < 4; ++nb)
            Opart2[orow * 64 + nb * 16 + lh] = oacc[mb][nb][r];
        }
      }
  } else {
    // finalize: o/l, epilogue o + 0.05*o^2*g[d] (out2==out1 identity)
#pragma unroll
    for (int mb = 0; mb < 2; ++mb)
#pragma unroll
      for (int r = 0; r < 4; ++r) {
        const float invl = 1.0f / lsum[mb][r];
        const int rows = base + mb * 16 + quad * 4 + r;
#pragma unroll
        for (int nb = 0; nb < 4; ++nb) {
          float o = oacc[mb][nb][r] * invl;
          float val = o + 0.05f * o * o * gate[nb * 16 + lh];
          attn[(size_t)(b * 2048 + rows) * 1024 + h * 64 + nb * 16 + lh] = f2bf(val);
        }
      }
  }
}

// ---------------- combine split-K partials (rows 512..2047) ----------------
__global__ __launch_bounds__(256) void combine_kernel(const float* __restrict__ Opart,
                                                      const float* __restrict__ Lpart,
                                                      const float* __restrict__ Opart2,
                                                      const float* __restrict__ Lpart2,
                                                      const float* __restrict__ gate,
                                                      u16* __restrict__ attn) {
  int idx = blockIdx.x * 256 + threadIdx.x;   // 0 .. 3145727
  int d = idx & 63;
  int r_all = idx >> 6;
  float o, l;
  int bh, s;
  if (r_all < 32768) {            // rows s >= 1024 (qi >= 8): 4 chunks
    o = Opart[idx] + Opart[idx + 2097152] + Opart[idx + 4194304] + Opart[idx + 6291456];
    l = Lpart[r_all] + Lpart[r_all + 32768] + Lpart[r_all + 65536] + Lpart[r_all + 98304];
    bh = r_all >> 10; s = 1024 + (r_all & 1023);
  } else {                        // rows 512..1023 (qi 4..7): 2 chunks
    const int r2 = r_all - 32768;
    const int i2 = idx - 2097152;
    o = Opart2[i2] + Opart2[i2 + 1048576];
    l = Lpart2[r2] + Lpart2[r2 + 16384];
    bh = r2 >> 9; s = 512 + (r2 & 511);
  }
  o /= l;
  float val = o + 0.05f * o * o * gate[d];
  int b = bh >> 4, h = bh & 15;
  attn[(size_t)(b * 2048 + s) * 1024 + h * 64 + d] = f2bf(val);
}

extern "C" void kernel_launch(void* const* d_in, const int* in_sizes, int n_in,
                              void* d_out, int out_size, void* d_ws, size_t ws_size,
                              hipStream_t stream) {
  (void)in_sizes; (void)n_in; (void)out_size; (void)ws_size;
  const float* x    = (const float*)d_in[0];
  const float* Wq   = (const float*)d_in[1];
  const float* Wk   = (const float*)d_in[2];
  const float* Wv   = (const float*)d_in[3];
  const float* Wo   = (const float*)d_in[4];
  const float* gate = (const float*)d_in[5];

  u16* ws    = (u16*)d_ws;
  u16* xbf   = ws;                    // 4096x1024 bf16 (qkv A input; attn out aliases later)
  u16* wbf   = xbf + 4194304;         // 3072x1024 (Wq|Wk|Wv rows)
  u16* wobf  = wbf + 3145728;         // 1024x1024
  u16* Qsb   = wobf + 1048576;        // (B,H,S,64) q/8
  u16* Kbb   = Qsb + 4194304;         // (B,H,S,64)
  u16* K2bb  = Kbb + 4194304;         // (B,H,S,64)
  u16* Vtb   = K2bb + 4194304;        // (B,H,64,S)  (written via LDS transpose in qkv epilogue)
  float* Opart  = (float*)(Vtb + 4194304); // 4 x 32 x 1024 x 64 fp32 (33.6 MB)
  float* Lpart  = Opart + 8388608;         // 4 x 32 x 1024 fp32
  float* Opart2 = Lpart + 131072;          // 2 x 32 x 512 x 64 fp32 (8.4 MB)
  float* Lpart2 = Opart2 + 2097152;        // 2 x 32 x 512 fp32
  u16* attnb = xbf;                   // alias: attn out (xbf dead after qkv_gemm)

  cvt_all<<<8192, 256, 0, stream>>>(x, Wq, Wk, Wv, Wo, xbf, wbf, wobf);
  qkv_gemm<<<dim3(24, 32), 256, 0, stream>>>(xbf, wbf, Vtb, Qsb, Kbb, K2bb);
  attn_kernel<<<dim3(44, 32), 256, 0, stream>>>(Qsb, Kbb, K2bb, Vtb, gate, attnb,
                                                Opart, Lpart, Opart2, Lpart2);
  combine_kernel<<<12288, 256, 0, stream>>>(Opart, Lpart, Opart2, Lpart2, gate, attnb);
  gemm_bt<float, 4, 2><<<dim3(16, 32), 256, 0, stream>>>(attnb, wobf, (float*)d_out, 1024, 1024);
}